// Round 14
// baseline (314.214 us; speedup 1.0000x reference)
//
#include <hip/hip_runtime.h>

typedef __attribute__((ext_vector_type(8))) short bf16x8;
typedef __attribute__((ext_vector_type(4))) float f32x4;

constexpr int L  = 384;
constexpr int R  = 256;
constexpr int D  = 128;
constexpr int NH = 8;
constexpr int HD = 16;
constexpr int FF = 512;

#define MFMA16(a, b, c) __builtin_amdgcn_mfma_f32_16x16x32_bf16((a), (b), (c), 0, 0, 0)

__device__ inline unsigned short f2bf(float f) {
    unsigned u = __builtin_bit_cast(unsigned, f);
    u += 0x7fffu + ((u >> 16) & 1u);          // round-to-nearest-even
    return (unsigned short)(u >> 16);
}

// triangular row from linear upper-tri index q (i<=j), L=384: off(i)=i*(769-i)/2
__device__ inline int tri_row(int q) {
    int i = (int)((769.0f - sqrtf((float)(591361 - 8 * q))) * 0.5f);
    while ((i + 1) * (769 - (i + 1)) / 2 <= q) ++i;
    while (i * (769 - i) / 2 > q) --i;
    return i;
}

// ---------------------------------------------------------------------------
// Prep: attn weights (w1p/w2p), LN3-fold constants, FRAGMENTIZED FFN weights
// ---------------------------------------------------------------------------
__global__ void k_prep(const float* __restrict__ w1,
                       const float* __restrict__ w2,
                       const float* __restrict__ ffw1,
                       const float* __restrict__ ffw2,
                       const float* __restrict__ g3,
                       const float* __restrict__ b3,
                       const float* __restrict__ ffb1,
                       unsigned short* __restrict__ w1p,
                       unsigned short* __restrict__ w2p,
                       unsigned short* __restrict__ w1gF,
                       unsigned short* __restrict__ w2tF,
                       float2* __restrict__ c1c2) {
    const int idx = blockIdx.x * 256 + threadIdx.x;   // 65536 threads
    {
        const int fi = idx >> 9, rem = idx & 511, l = rem >> 3, e = rem & 7;
        const int lr2 = l & 15, lg2 = l >> 4;
        const int n = fi >> 2, ks = fi & 3;
        const int ch = n * 16 + lr2, k = ks * 32 + lg2 * 8 + e;
        w1gF[idx] = f2bf(g3[k] * ffw1[(size_t)k * FF + ch]);
    }
    {
        const int fi = idx >> 9, rem = idx & 511, l = rem >> 3, e = rem & 7;
        const int lr2 = l & 15, lg2 = l >> 4;
        const int n = fi >> 4, Ks = fi & 15;
        const int ch = n * 16 + lr2, k = Ks * 32 + lg2 * 8 + e;
        w2tF[idx] = f2bf(ffw2[(size_t)k * D + ch]);
    }
    if (idx < 16 * D) {
        const int n = idx >> 7, k = idx & 127;
        w1p[idx] = (n < NH) ? f2bf(w1[(size_t)k * NH + n]) : (unsigned short)0;
        w2p[idx] = f2bf(w2[(size_t)k * HD + n]);
    }
    if (blockIdx.x < 2) {
        const int n = blockIdx.x * 256 + threadIdx.x;   // 0..511
        float c1 = 0.f, c2 = 0.f;
        for (int k = 0; k < D; ++k) {
            const float w = ffw1[(size_t)k * FF + n];
            c1 += g3[k] * w;
            c2 += b3[k] * w;
        }
        c1c2[n] = make_float2(c1, c2 + ffb1[n]);
    }
}

// ---------------------------------------------------------------------------
// Kernel 1: symmetrize + LN1 + logits via MFMA, upper triangle only
// ---------------------------------------------------------------------------
__global__ void k_pair_logits(const float* __restrict__ x,
                              const float* __restrict__ g,
                              const float* __restrict__ bt,
                              const unsigned short* __restrict__ w1p,
                              const float* __restrict__ b1,
                              float* __restrict__ logits) {
    __shared__ unsigned short nrm[64][136];
    __shared__ int ij[64];
    const int tid = threadIdx.x;
    const int q0 = blockIdx.x * 64;

    {
        const int pr = tid >> 2, part = tid & 3;
        const int q = q0 + pr;
        const int i = tri_row(q);
        const int j = i + (q - i * (769 - i) / 2);
        if (part == 0) ij[pr] = (i << 16) | j;
        const float* xa = x + ((size_t)i * L + j) * D + part * 32;
        const float* xb = x + ((size_t)j * L + i) * D + part * 32;
        float v[32];
        float s = 0.f, sq = 0.f;
        #pragma unroll
        for (int q8 = 0; q8 < 8; ++q8) {
            const float4 a = ((const float4*)xa)[q8];
            const float4 b = ((const float4*)xb)[q8];
            const float t0 = 0.5f * (a.x + b.x), t1 = 0.5f * (a.y + b.y);
            const float t2 = 0.5f * (a.z + b.z), t3 = 0.5f * (a.w + b.w);
            v[q8*4+0] = t0; v[q8*4+1] = t1; v[q8*4+2] = t2; v[q8*4+3] = t3;
            s  += t0 + t1 + t2 + t3;
            sq += t0*t0 + t1*t1 + t2*t2 + t3*t3;
        }
        s  += __shfl_xor(s, 1);  s  += __shfl_xor(s, 2);
        sq += __shfl_xor(sq, 1); sq += __shfl_xor(sq, 2);
        const float mean = s * (1.0f / D);
        const float rstd = rsqrtf(sq * (1.0f / D) - mean * mean + 1e-5f);
        #pragma unroll
        for (int q8 = 0; q8 < 8; ++q8) {
            const int c = part * 32 + q8 * 4;
            ushort4 pk;
            pk.x = f2bf((v[q8*4+0] - mean) * rstd * g[c+0] + bt[c+0]);
            pk.y = f2bf((v[q8*4+1] - mean) * rstd * g[c+1] + bt[c+1]);
            pk.z = f2bf((v[q8*4+2] - mean) * rstd * g[c+2] + bt[c+2]);
            pk.w = f2bf((v[q8*4+3] - mean) * rstd * g[c+3] + bt[c+3]);
            *(ushort4*)(&nrm[pr][c]) = pk;
        }
    }
    __syncthreads();

    {
        const int wv = tid >> 6, lane = tid & 63;
        const int lr = lane & 15, lg = lane >> 4;
        f32x4 acc = {0.f, 0.f, 0.f, 0.f};
        #pragma unroll
        for (int ks = 0; ks < 4; ++ks) {
            bf16x8 a = *(const bf16x8*)(&nrm[wv * 16 + lr][ks * 32 + lg * 8]);
            bf16x8 b = *(const bf16x8*)(w1p + (size_t)lr * D + ks * 32 + lg * 8);
            acc = MFMA16(a, b, acc);
        }
        if (lr < NH) {
            #pragma unroll
            for (int r = 0; r < 4; ++r) {
                const int pl = wv * 16 + lg * 4 + r;
                const int pij = ij[pl];
                const int pi = pij >> 16, pj = pij & 0xffff;
                const float val = acc[r] + b1[lr];
                logits[((size_t)pi * L + pj) * NH + lr] = val;
                logits[((size_t)pj * L + pi) * NH + lr] = val;
            }
        }
    }
}

// ---------------------------------------------------------------------------
// Kernel 2: softmax over j for each (i,h); logits f32 -> attnT bf16 [h][i][j]
// ---------------------------------------------------------------------------
__global__ void k_softmax(const float* __restrict__ logits,
                          unsigned short* __restrict__ attnT) {
    const int wave = blockIdx.x * 4 + (threadIdx.x >> 6);
    const int lane = threadIdx.x & 63;
    const int i = wave >> 3, h = wave & 7;

    float v[6];
    float mx = -1e30f;
    #pragma unroll
    for (int t = 0; t < 6; ++t) {
        const int j = lane + t * 64;
        v[t] = logits[((size_t)i * L + j) * NH + h];
        mx = fmaxf(mx, v[t]);
    }
    #pragma unroll
    for (int msk = 32; msk; msk >>= 1) mx = fmaxf(mx, __shfl_xor(mx, msk));

    float s = 0.0f;
    #pragma unroll
    for (int t = 0; t < 6; ++t) { v[t] = __expf(v[t] - mx); s += v[t]; }
    #pragma unroll
    for (int msk = 32; msk; msk >>= 1) s += __shfl_xor(s, msk);
    const float inv = 1.0f / s;

    #pragma unroll
    for (int t = 0; t < 6; ++t) {
        const int j = lane + t * 64;
        attnT[((size_t)h * L + i) * L + j] = f2bf(v[t] * inv);
    }
}

// ---------------------------------------------------------------------------
// Kernel 3: values = LN2(m) @ w2 + b2 -> VtT bf16 [n = r*16+d][j]
// ---------------------------------------------------------------------------
__global__ void k_values(const float* __restrict__ min_,
                         const float* __restrict__ g,
                         const float* __restrict__ bt,
                         const unsigned short* __restrict__ w2p,
                         const float* __restrict__ b2,
                         unsigned short* __restrict__ VtT) {
    __shared__ unsigned short nrm[128][136];
    const int tid = threadIdx.x;
    const int r  = blockIdx.x;
    const int j0 = blockIdx.y * 128;

    #pragma unroll
    for (int half = 0; half < 2; ++half) {
        const int row  = half * 64 + (tid >> 2);
        const int part = tid & 3;
        const float* src = min_ + ((size_t)r * L + j0 + row) * D + part * 32;
        float v[32];
        float s = 0.f, sq = 0.f;
        #pragma unroll
        for (int q = 0; q < 8; ++q) {
            const float4 a = ((const float4*)src)[q];
            v[q*4+0] = a.x; v[q*4+1] = a.y; v[q*4+2] = a.z; v[q*4+3] = a.w;
            s  += a.x + a.y + a.z + a.w;
            sq += a.x*a.x + a.y*a.y + a.z*a.z + a.w*a.w;
        }
        s  += __shfl_xor(s, 1);  s  += __shfl_xor(s, 2);
        sq += __shfl_xor(sq, 1); sq += __shfl_xor(sq, 2);
        const float mean = s * (1.0f / D);
        const float rstd = rsqrtf(sq * (1.0f / D) - mean * mean + 1e-5f);
        #pragma unroll
        for (int q = 0; q < 8; ++q) {
            const int c = part * 32 + q * 4;
            ushort4 pk;
            pk.x = f2bf((v[q*4+0] - mean) * rstd * g[c+0] + bt[c+0]);
            pk.y = f2bf((v[q*4+1] - mean) * rstd * g[c+1] + bt[c+1]);
            pk.z = f2bf((v[q*4+2] - mean) * rstd * g[c+2] + bt[c+2]);
            pk.w = f2bf((v[q*4+3] - mean) * rstd * g[c+3] + bt[c+3]);
            *(ushort4*)(&nrm[row][c]) = pk;
        }
    }
    __syncthreads();

    {
        const int wv = tid >> 6, lane = tid & 63;
        const int lr = lane & 15, lg = lane >> 4;
        f32x4 acc[2];
        acc[0] = (f32x4){0.f, 0.f, 0.f, 0.f};
        acc[1] = (f32x4){0.f, 0.f, 0.f, 0.f};
        #pragma unroll
        for (int ks = 0; ks < 4; ++ks) {
            bf16x8 b = *(const bf16x8*)(w2p + (size_t)lr * D + ks * 32 + lg * 8);
            #pragma unroll
            for (int mt = 0; mt < 2; ++mt) {
                bf16x8 a = *(const bf16x8*)(&nrm[wv * 32 + mt * 16 + lr][ks * 32 + lg * 8]);
                acc[mt] = MFMA16(a, b, acc[mt]);
            }
        }
        const float bb = b2[lr];
        #pragma unroll
        for (int mt = 0; mt < 2; ++mt) {
            ushort4 pk;
            pk.x = f2bf(acc[mt][0] + bb);
            pk.y = f2bf(acc[mt][1] + bb);
            pk.z = f2bf(acc[mt][2] + bb);
            pk.w = f2bf(acc[mt][3] + bb);
            *(ushort4*)(VtT + (size_t)(r * HD + lr) * L + j0 + wv * 32 + mt * 16 + lg * 4) = pk;
        }
    }
}

// ---------------------------------------------------------------------------
// Kernel 4: einsum via MFMA, reg-dbuf'd fragments + XCD-aware swizzle:
// 768 blocks flattened 1-D; swz=(orig%8)*96+orig/8 gives each XCD one head
// (attnT slice 288 KB + VtT 3.15 MB stay L2-resident per XCD).
// ---------------------------------------------------------------------------
__global__ void k_attn_out(const unsigned short* __restrict__ attnT,
                           const unsigned short* __restrict__ VtT,
                           const float* __restrict__ min_,
                           float* __restrict__ out) {
    const int orig = blockIdx.x;                 // 0..767
    const int swz  = (orig & 7) * 96 + (orig >> 3);
    const int h    = swz / 96;                   // == orig & 7
    const int rem  = swz % 96;
    const int n0   = (rem / 3) * 128;
    const int i0   = (rem % 3) * 128;

    const int tid = threadIdx.x, wv = tid >> 6, lane = tid & 63;
    const int lr = lane & 15, lg = lane >> 4;
    const int wio = (wv >> 1) * 64, wno = (wv & 1) * 64;
    const unsigned short* Abase = attnT + (size_t)h * L * L;

    f32x4 acc[4][4];
    #pragma unroll
    for (int a = 0; a < 4; ++a)
        #pragma unroll
        for (int b = 0; b < 4; ++b) acc[a][b] = (f32x4){0.f, 0.f, 0.f, 0.f};

    bf16x8 af[4], bf[4], afn[4], bfn[4];
    #pragma unroll
    for (int mt = 0; mt < 4; ++mt)
        af[mt] = *(const bf16x8*)(Abase + (size_t)(i0 + wio + mt * 16 + lr) * L + lg * 8);
    #pragma unroll
    for (int nt = 0; nt < 4; ++nt)
        bf[nt] = *(const bf16x8*)(VtT + (size_t)(n0 + wno + nt * 16 + lr) * L + lg * 8);

    for (int ks = 0; ks < 12; ++ks) {
        if (ks < 11) {
            const int ko = (ks + 1) * 32 + lg * 8;
            #pragma unroll
            for (int mt = 0; mt < 4; ++mt)
                afn[mt] = *(const bf16x8*)(Abase + (size_t)(i0 + wio + mt * 16 + lr) * L + ko);
            #pragma unroll
            for (int nt = 0; nt < 4; ++nt)
                bfn[nt] = *(const bf16x8*)(VtT + (size_t)(n0 + wno + nt * 16 + lr) * L + ko);
        }
        #pragma unroll
        for (int mt = 0; mt < 4; ++mt)
            #pragma unroll
            for (int nt = 0; nt < 4; ++nt)
                acc[mt][nt] = MFMA16(af[mt], bf[nt], acc[mt][nt]);
        #pragma unroll
        for (int q = 0; q < 4; ++q) { af[q] = afn[q]; bf[q] = bfn[q]; }
    }

    #pragma unroll
    for (int mt = 0; mt < 4; ++mt) {
        #pragma unroll
        for (int nt = 0; nt < 4; ++nt) {
            const int nbase = n0 + wno + nt * 16;
            const int rrow  = nbase >> 4;
            #pragma unroll
            for (int r = 0; r < 4; ++r) {
                const int i = i0 + wio + mt * 16 + lg * 4 + r;
                const size_t gidx = ((size_t)rrow * L + i) * D + h * HD + lr;
                out[gidx] = min_[gidx] + acc[mt][nt][r];
            }
        }
    }
}

// ---------------------------------------------------------------------------
// Kernel 5: FUSED FFN v5 — 32 rows/block (LDS 24.75 KB), 512 thr, 8 waves
// as 2M(16 rows) x 4N. 4 blocks/CU = 32 waves/CU (wave-slot cap). Same
// fragment indices & reg-pipelined weights as v4. Single out pointer.
// ---------------------------------------------------------------------------
__global__ __launch_bounds__(512, 8) void k_ffn(
                      const unsigned short* __restrict__ w1gF,
                      const float2* __restrict__ c1c2,
                      const unsigned short* __restrict__ w2tF,
                      const float* __restrict__ ffb2,
                      float* out) {
    __shared__ unsigned short At[32 * 128];     // 8 KB, row-XOR swizzled
    __shared__ unsigned short hid[2][32 * 128]; // 2 x 8 KB, swizzled
    __shared__ float2 stats[32];                // (rstd, mu*rstd)
    const int tid = threadIdx.x;
    const size_t row0 = (size_t)blockIdx.x * 32;

    const int wv = tid >> 6, lane = tid & 63;
    const int lr = lane & 15, lg = lane >> 4;
    const int wm = wv >> 2, wn = wv & 3;          // 2(M:16rows) x 4(N:32cols)

    // ---- preload W1 fragments for kc=0 (overlaps A-staging) ----
    bf16x8 w1f[8], w2f[8];
    #pragma unroll
    for (int ks = 0; ks < 4; ++ks)
        #pragma unroll
        for (int nt = 0; nt < 2; ++nt) {
            const int fi = (0 * 8 + wn * 2 + nt) * 4 + ks;
            w1f[ks * 2 + nt] = *(const bf16x8*)((const char*)w1gF + fi * 1024 + lane * 16);
        }

    // ---- Stage A + inline LN3 stats: 16 threads/row x 8 f32 each ----
    {
        const int rr = tid >> 4, part = tid & 15;
        const float* src = out + (row0 + rr) * D + part * 8;
        const float4 a0 = ((const float4*)src)[0];
        const float4 a1 = ((const float4*)src)[1];
        float s  = a0.x+a0.y+a0.z+a0.w + a1.x+a1.y+a1.z+a1.w;
        float sq = a0.x*a0.x+a0.y*a0.y+a0.z*a0.z+a0.w*a0.w
                 + a1.x*a1.x+a1.y*a1.y+a1.z*a1.z+a1.w*a1.w;
        s  += __shfl_xor(s, 1);  s  += __shfl_xor(s, 2);
        s  += __shfl_xor(s, 4);  s  += __shfl_xor(s, 8);
        sq += __shfl_xor(sq, 1); sq += __shfl_xor(sq, 2);
        sq += __shfl_xor(sq, 4); sq += __shfl_xor(sq, 8);
        if (part == 0) {
            const float mean = s * (1.0f / D);
            const float rstd = rsqrtf(sq * (1.0f / D) - mean * mean + 1e-5f);
            stats[rr] = make_float2(rstd, mean * rstd);
        }
        const int xr = (rr & 7) << 4;
        char* rowp = (char*)(At + rr * 128);
        unsigned q0 = (unsigned)f2bf(a0.x) | ((unsigned)f2bf(a0.y) << 16);
        unsigned q1 = (unsigned)f2bf(a0.z) | ((unsigned)f2bf(a0.w) << 16);
        unsigned q2 = (unsigned)f2bf(a1.x) | ((unsigned)f2bf(a1.y) << 16);
        unsigned q3 = (unsigned)f2bf(a1.z) | ((unsigned)f2bf(a1.w) << 16);
        uint4 pk = {q0, q1, q2, q3};
        *(uint4*)(rowp + ((part * 16) ^ xr)) = pk;
    }

    // ---- preload W2 fragments for kc=0 ----
    #pragma unroll
    for (int ks = 0; ks < 4; ++ks)
        #pragma unroll
        for (int nt = 0; nt < 2; ++nt) {
            const int fi = (wn * 2 + nt) * 16 + 0 * 4 + ks;
            w2f[ks * 2 + nt] = *(const bf16x8*)((const char*)w2tF + fi * 1024 + lane * 16);
        }

    __syncthreads();

    f32x4 acc2[2];
    acc2[0] = (f32x4){0.f, 0.f, 0.f, 0.f};
    acc2[1] = (f32x4){0.f, 0.f, 0.f, 0.f};

    #pragma unroll
    for (int kc = 0; kc < 4; ++kc) {
        const int p = kc & 1;

        // ---- GEMM1-chunk: hid[32 x 128(kc)] = At(32x128) @ W1-chunk ----
        {
            f32x4 acc1[2];
            acc1[0] = (f32x4){0.f, 0.f, 0.f, 0.f};
            acc1[1] = (f32x4){0.f, 0.f, 0.f, 0.f};

            #pragma unroll
            for (int ks = 0; ks < 4; ++ks) {
                const int row = wm * 16 + lr;
                bf16x8 af = *(const bf16x8*)((char*)(At + row * 128) +
                             ((ks * 64 + lg * 16) ^ ((row & 7) << 4)));
                acc1[0] = MFMA16(af, w1f[ks * 2 + 0], acc1[0]);
                acc1[1] = MFMA16(af, w1f[ks * 2 + 1], acc1[1]);
            }

            #pragma unroll
            for (int nt = 0; nt < 2; ++nt) {
                const int chl = wn * 32 + nt * 16 + lr;        // 0..127
                const float2 cc = c1c2[kc * 128 + chl];
                #pragma unroll
                for (int r = 0; r < 4; ++r) {
                    const int row = wm * 16 + lg * 4 + r;
                    const float2 st = stats[row];
                    const float pre = st.x * acc1[nt][r] - st.y * cc.x + cc.y;
                    *(unsigned short*)((char*)(hid[p] + row * 128) +
                        ((chl * 2) ^ ((row & 7) << 4))) = f2bf(fmaxf(pre, 0.f));
                }
            }
        }
        __syncthreads();

        // refill W1 for kc+1 AFTER the barrier (overlaps GEMM2)
        if (kc < 3) {
            #pragma unroll
            for (int ks = 0; ks < 4; ++ks)
                #pragma unroll
                for (int nt = 0; nt < 2; ++nt) {
                    const int fi = ((kc + 1) * 8 + wn * 2 + nt) * 4 + ks;
                    w1f[ks * 2 + nt] = *(const bf16x8*)((const char*)w1gF + fi * 1024 + lane * 16);
                }
        }

        // ---- GEMM2-chunk: acc2 += hid-chunk(32x128) @ W2-chunk ----
        {
            #pragma unroll
            for (int ks = 0; ks < 4; ++ks) {
                const int row = wm * 16 + lr;
                bf16x8 hf = *(const bf16x8*)((char*)(hid[p] + row * 128) +
                             ((ks * 64 + lg * 16) ^ ((row & 7) << 4)));
                acc2[0] = MFMA16(hf, w2f[ks * 2 + 0], acc2[0]);
                acc2[1] = MFMA16(hf, w2f[ks * 2 + 1], acc2[1]);
            }
        }

        // refill W2 for kc+1 (overlaps next GEMM1)
        if (kc < 3) {
            #pragma unroll
            for (int ks = 0; ks < 4; ++ks)
                #pragma unroll
                for (int nt = 0; nt < 2; ++nt) {
                    const int fi = (wn * 2 + nt) * 16 + (kc + 1) * 4 + ks;
                    w2f[ks * 2 + nt] = *(const bf16x8*)((const char*)w2tF + fi * 1024 + lane * 16);
                }
        }
    }

    // ---- epilogue: out += acc2 + ffb2 ----
    #pragma unroll
    for (int nt = 0; nt < 2; ++nt) {
        const int ch = wn * 32 + nt * 16 + lr;
        const float bb = ffb2[ch];
        #pragma unroll
        for (int r = 0; r < 4; ++r) {
            const size_t gi = (row0 + wm * 16 + lg * 4 + r) * (size_t)D + ch;
            out[gi] = out[gi] + acc2[nt][r] + bb;
        }
    }
}

// ---------------------------------------------------------------------------
extern "C" void kernel_launch(void* const* d_in, const int* in_sizes, int n_in,
                              void* d_out, int out_size, void* d_ws, size_t ws_size,
                              hipStream_t stream) {
    const float* x     = (const float*)d_in[0];
    const float* m     = (const float*)d_in[1];
    const float* ln1_g = (const float*)d_in[2];
    const float* ln1_b = (const float*)d_in[3];
    const float* ln2_g = (const float*)d_in[4];
    const float* ln2_b = (const float*)d_in[5];
    const float* ln3_g = (const float*)d_in[6];
    const float* ln3_b = (const float*)d_in[7];
    const float* w1    = (const float*)d_in[8];
    const float* b1    = (const float*)d_in[9];
    const float* w2    = (const float*)d_in[10];
    const float* b2    = (const float*)d_in[11];
    const float* ffw1  = (const float*)d_in[12];
    const float* ffb1  = (const float*)d_in[13];
    const float* ffw2  = (const float*)d_in[14];
    const float* ffb2  = (const float*)d_in[15];

    float* out = (float*)d_out;

    char* wsp = (char*)d_ws;
    float*          logits = (float*)wsp;              wsp += (size_t)L*L*NH*4;   // 4.72 MB
    unsigned short* attnT  = (unsigned short*)wsp;     wsp += (size_t)NH*L*L*2;   // 2.36 MB
    unsigned short* VtT    = (unsigned short*)wsp;     wsp += (size_t)R*HD*L*2;   // 3.15 MB
    unsigned short* w1gF   = (unsigned short*)wsp;     wsp += (size_t)FF*D*2;     // 128 KB
    unsigned short* w2tF   = (unsigned short*)wsp;     wsp += (size_t)D*FF*2;     // 128 KB
    unsigned short* w1p    = (unsigned short*)wsp;     wsp += (size_t)16*D*2;     // 4 KB
    unsigned short* w2p    = (unsigned short*)wsp;     wsp += (size_t)16*D*2;     // 4 KB
    float2*         c1c2   = (float2*)wsp;             wsp += (size_t)FF*8;       // 4 KB

    k_prep<<<(FF * D) / 256, 256, 0, stream>>>(w1, w2, ffw1, ffw2,
                                               ln3_g, ln3_b, ffb1,
                                               w1p, w2p, w1gF, w2tF, c1c2);

    // upper-triangle pair count: 384*385/2 = 73920 -> 1155 blocks of 64
    k_pair_logits<<<1155, 256, 0, stream>>>(x, ln1_g, ln1_b, w1p, b1, logits);
    k_softmax<<<(L * NH) / 4, 256, 0, stream>>>(logits, attnT);

    dim3 g3(R, L / 128);
    k_values<<<g3, 256, 0, stream>>>(m, ln2_g, ln2_b, w2p, b2, VtT);

    // 768 blocks flattened 1-D (3 i-tiles x 32 n-tiles x 8 heads)
    k_attn_out<<<768, 256, 0, stream>>>(attnT, VtT, m, out);

    k_ffn<<<(R * L) / 32, 512, 0, stream>>>(w1gF, c1c2, w2tF, ffb2, out);
}

// Round 15
// 208.446 us; speedup vs baseline: 1.5074x; 1.5074x over previous
//
#include <hip/hip_runtime.h>

typedef __attribute__((ext_vector_type(8))) short bf16x8;
typedef __attribute__((ext_vector_type(4))) float f32x4;

constexpr int L  = 384;
constexpr int R  = 256;
constexpr int D  = 128;
constexpr int NH = 8;
constexpr int HD = 16;
constexpr int FF = 512;

#define MFMA16(a, b, c) __builtin_amdgcn_mfma_f32_16x16x32_bf16((a), (b), (c), 0, 0, 0)

__device__ inline unsigned short f2bf(float f) {
    unsigned u = __builtin_bit_cast(unsigned, f);
    u += 0x7fffu + ((u >> 16) & 1u);          // round-to-nearest-even
    return (unsigned short)(u >> 16);
}

// triangular row from linear upper-tri index q (i<=j), L=384: off(i)=i*(769-i)/2
__device__ inline int tri_row(int q) {
    int i = (int)((769.0f - sqrtf((float)(591361 - 8 * q))) * 0.5f);
    while ((i + 1) * (769 - (i + 1)) / 2 <= q) ++i;
    while (i * (769 - i) / 2 > q) --i;
    return i;
}

// ---------------------------------------------------------------------------
// Prep: attn weights (w1p/w2p), LN3-fold constants, FRAGMENTIZED FFN weights
// ---------------------------------------------------------------------------
__global__ void k_prep(const float* __restrict__ w1,
                       const float* __restrict__ w2,
                       const float* __restrict__ ffw1,
                       const float* __restrict__ ffw2,
                       const float* __restrict__ g3,
                       const float* __restrict__ b3,
                       const float* __restrict__ ffb1,
                       unsigned short* __restrict__ w1p,
                       unsigned short* __restrict__ w2p,
                       unsigned short* __restrict__ w1gF,
                       unsigned short* __restrict__ w2tF,
                       float2* __restrict__ c1c2) {
    const int idx = blockIdx.x * 256 + threadIdx.x;   // 65536 threads
    {
        const int fi = idx >> 9, rem = idx & 511, l = rem >> 3, e = rem & 7;
        const int lr2 = l & 15, lg2 = l >> 4;
        const int n = fi >> 2, ks = fi & 3;
        const int ch = n * 16 + lr2, k = ks * 32 + lg2 * 8 + e;
        w1gF[idx] = f2bf(g3[k] * ffw1[(size_t)k * FF + ch]);
    }
    {
        const int fi = idx >> 9, rem = idx & 511, l = rem >> 3, e = rem & 7;
        const int lr2 = l & 15, lg2 = l >> 4;
        const int n = fi >> 4, Ks = fi & 15;
        const int ch = n * 16 + lr2, k = Ks * 32 + lg2 * 8 + e;
        w2tF[idx] = f2bf(ffw2[(size_t)k * D + ch]);
    }
    if (idx < 16 * D) {
        const int n = idx >> 7, k = idx & 127;
        w1p[idx] = (n < NH) ? f2bf(w1[(size_t)k * NH + n]) : (unsigned short)0;
        w2p[idx] = f2bf(w2[(size_t)k * HD + n]);
    }
    if (blockIdx.x < 2) {
        const int n = blockIdx.x * 256 + threadIdx.x;   // 0..511
        float c1 = 0.f, c2 = 0.f;
        for (int k = 0; k < D; ++k) {
            const float w = ffw1[(size_t)k * FF + n];
            c1 += g3[k] * w;
            c2 += b3[k] * w;
        }
        c1c2[n] = make_float2(c1, c2 + ffb1[n]);
    }
}

// ---------------------------------------------------------------------------
// Kernel 1: symmetrize + LN1 + logits via MFMA, upper triangle only
// ---------------------------------------------------------------------------
__global__ void k_pair_logits(const float* __restrict__ x,
                              const float* __restrict__ g,
                              const float* __restrict__ bt,
                              const unsigned short* __restrict__ w1p,
                              const float* __restrict__ b1,
                              float* __restrict__ logits) {
    __shared__ unsigned short nrm[64][136];
    __shared__ int ij[64];
    const int tid = threadIdx.x;
    const int q0 = blockIdx.x * 64;

    {
        const int pr = tid >> 2, part = tid & 3;
        const int q = q0 + pr;
        const int i = tri_row(q);
        const int j = i + (q - i * (769 - i) / 2);
        if (part == 0) ij[pr] = (i << 16) | j;
        const float* xa = x + ((size_t)i * L + j) * D + part * 32;
        const float* xb = x + ((size_t)j * L + i) * D + part * 32;
        float v[32];
        float s = 0.f, sq = 0.f;
        #pragma unroll
        for (int q8 = 0; q8 < 8; ++q8) {
            const float4 a = ((const float4*)xa)[q8];
            const float4 b = ((const float4*)xb)[q8];
            const float t0 = 0.5f * (a.x + b.x), t1 = 0.5f * (a.y + b.y);
            const float t2 = 0.5f * (a.z + b.z), t3 = 0.5f * (a.w + b.w);
            v[q8*4+0] = t0; v[q8*4+1] = t1; v[q8*4+2] = t2; v[q8*4+3] = t3;
            s  += t0 + t1 + t2 + t3;
            sq += t0*t0 + t1*t1 + t2*t2 + t3*t3;
        }
        s  += __shfl_xor(s, 1);  s  += __shfl_xor(s, 2);
        sq += __shfl_xor(sq, 1); sq += __shfl_xor(sq, 2);
        const float mean = s * (1.0f / D);
        const float rstd = rsqrtf(sq * (1.0f / D) - mean * mean + 1e-5f);
        #pragma unroll
        for (int q8 = 0; q8 < 8; ++q8) {
            const int c = part * 32 + q8 * 4;
            ushort4 pk;
            pk.x = f2bf((v[q8*4+0] - mean) * rstd * g[c+0] + bt[c+0]);
            pk.y = f2bf((v[q8*4+1] - mean) * rstd * g[c+1] + bt[c+1]);
            pk.z = f2bf((v[q8*4+2] - mean) * rstd * g[c+2] + bt[c+2]);
            pk.w = f2bf((v[q8*4+3] - mean) * rstd * g[c+3] + bt[c+3]);
            *(ushort4*)(&nrm[pr][c]) = pk;
        }
    }
    __syncthreads();

    {
        const int wv = tid >> 6, lane = tid & 63;
        const int lr = lane & 15, lg = lane >> 4;
        f32x4 acc = {0.f, 0.f, 0.f, 0.f};
        #pragma unroll
        for (int ks = 0; ks < 4; ++ks) {
            bf16x8 a = *(const bf16x8*)(&nrm[wv * 16 + lr][ks * 32 + lg * 8]);
            bf16x8 b = *(const bf16x8*)(w1p + (size_t)lr * D + ks * 32 + lg * 8);
            acc = MFMA16(a, b, acc);
        }
        if (lr < NH) {
            #pragma unroll
            for (int r = 0; r < 4; ++r) {
                const int pl = wv * 16 + lg * 4 + r;
                const int pij = ij[pl];
                const int pi = pij >> 16, pj = pij & 0xffff;
                const float val = acc[r] + b1[lr];
                logits[((size_t)pi * L + pj) * NH + lr] = val;
                logits[((size_t)pj * L + pi) * NH + lr] = val;
            }
        }
    }
}

// ---------------------------------------------------------------------------
// Kernel 2: softmax over j for each (i,h); logits f32 -> attnT bf16 [h][i][j]
// ---------------------------------------------------------------------------
__global__ void k_softmax(const float* __restrict__ logits,
                          unsigned short* __restrict__ attnT) {
    const int wave = blockIdx.x * 4 + (threadIdx.x >> 6);
    const int lane = threadIdx.x & 63;
    const int i = wave >> 3, h = wave & 7;

    float v[6];
    float mx = -1e30f;
    #pragma unroll
    for (int t = 0; t < 6; ++t) {
        const int j = lane + t * 64;
        v[t] = logits[((size_t)i * L + j) * NH + h];
        mx = fmaxf(mx, v[t]);
    }
    #pragma unroll
    for (int msk = 32; msk; msk >>= 1) mx = fmaxf(mx, __shfl_xor(mx, msk));

    float s = 0.0f;
    #pragma unroll
    for (int t = 0; t < 6; ++t) { v[t] = __expf(v[t] - mx); s += v[t]; }
    #pragma unroll
    for (int msk = 32; msk; msk >>= 1) s += __shfl_xor(s, msk);
    const float inv = 1.0f / s;

    #pragma unroll
    for (int t = 0; t < 6; ++t) {
        const int j = lane + t * 64;
        attnT[((size_t)h * L + i) * L + j] = f2bf(v[t] * inv);
    }
}

// ---------------------------------------------------------------------------
// Kernel 3: values = LN2(m) @ w2 + b2 -> VtT bf16 [n = r*16+d][j]
// ---------------------------------------------------------------------------
__global__ void k_values(const float* __restrict__ min_,
                         const float* __restrict__ g,
                         const float* __restrict__ bt,
                         const unsigned short* __restrict__ w2p,
                         const float* __restrict__ b2,
                         unsigned short* __restrict__ VtT) {
    __shared__ unsigned short nrm[128][136];
    const int tid = threadIdx.x;
    const int r  = blockIdx.x;
    const int j0 = blockIdx.y * 128;

    #pragma unroll
    for (int half = 0; half < 2; ++half) {
        const int row  = half * 64 + (tid >> 2);
        const int part = tid & 3;
        const float* src = min_ + ((size_t)r * L + j0 + row) * D + part * 32;
        float v[32];
        float s = 0.f, sq = 0.f;
        #pragma unroll
        for (int q = 0; q < 8; ++q) {
            const float4 a = ((const float4*)src)[q];
            v[q*4+0] = a.x; v[q*4+1] = a.y; v[q*4+2] = a.z; v[q*4+3] = a.w;
            s  += a.x + a.y + a.z + a.w;
            sq += a.x*a.x + a.y*a.y + a.z*a.z + a.w*a.w;
        }
        s  += __shfl_xor(s, 1);  s  += __shfl_xor(s, 2);
        sq += __shfl_xor(sq, 1); sq += __shfl_xor(sq, 2);
        const float mean = s * (1.0f / D);
        const float rstd = rsqrtf(sq * (1.0f / D) - mean * mean + 1e-5f);
        #pragma unroll
        for (int q = 0; q < 8; ++q) {
            const int c = part * 32 + q * 4;
            ushort4 pk;
            pk.x = f2bf((v[q*4+0] - mean) * rstd * g[c+0] + bt[c+0]);
            pk.y = f2bf((v[q*4+1] - mean) * rstd * g[c+1] + bt[c+1]);
            pk.z = f2bf((v[q*4+2] - mean) * rstd * g[c+2] + bt[c+2]);
            pk.w = f2bf((v[q*4+3] - mean) * rstd * g[c+3] + bt[c+3]);
            *(ushort4*)(&nrm[row][c]) = pk;
        }
    }
    __syncthreads();

    {
        const int wv = tid >> 6, lane = tid & 63;
        const int lr = lane & 15, lg = lane >> 4;
        f32x4 acc[2];
        acc[0] = (f32x4){0.f, 0.f, 0.f, 0.f};
        acc[1] = (f32x4){0.f, 0.f, 0.f, 0.f};
        #pragma unroll
        for (int ks = 0; ks < 4; ++ks) {
            bf16x8 b = *(const bf16x8*)(w2p + (size_t)lr * D + ks * 32 + lg * 8);
            #pragma unroll
            for (int mt = 0; mt < 2; ++mt) {
                bf16x8 a = *(const bf16x8*)(&nrm[wv * 32 + mt * 16 + lr][ks * 32 + lg * 8]);
                acc[mt] = MFMA16(a, b, acc[mt]);
            }
        }
        const float bb = b2[lr];
        #pragma unroll
        for (int mt = 0; mt < 2; ++mt) {
            ushort4 pk;
            pk.x = f2bf(acc[mt][0] + bb);
            pk.y = f2bf(acc[mt][1] + bb);
            pk.z = f2bf(acc[mt][2] + bb);
            pk.w = f2bf(acc[mt][3] + bb);
            *(ushort4*)(VtT + (size_t)(r * HD + lr) * L + j0 + wv * 32 + mt * 16 + lg * 4) = pk;
        }
    }
}

// ---------------------------------------------------------------------------
// Kernel 4: einsum via MFMA, reg-dbuf'd fragments + XCD-aware swizzle:
// 768 blocks flattened 1-D; swz=(orig%8)*96+orig/8 gives each XCD one head
// (attnT slice 288 KB + VtT 3.15 MB stay L2-resident per XCD).
// ---------------------------------------------------------------------------
__global__ void k_attn_out(const unsigned short* __restrict__ attnT,
                           const unsigned short* __restrict__ VtT,
                           const float* __restrict__ min_,
                           float* __restrict__ out) {
    const int orig = blockIdx.x;                 // 0..767
    const int swz  = (orig & 7) * 96 + (orig >> 3);
    const int h    = swz / 96;                   // == orig & 7
    const int rem  = swz % 96;
    const int n0   = (rem / 3) * 128;
    const int i0   = (rem % 3) * 128;

    const int tid = threadIdx.x, wv = tid >> 6, lane = tid & 63;
    const int lr = lane & 15, lg = lane >> 4;
    const int wio = (wv >> 1) * 64, wno = (wv & 1) * 64;
    const unsigned short* Abase = attnT + (size_t)h * L * L;

    f32x4 acc[4][4];
    #pragma unroll
    for (int a = 0; a < 4; ++a)
        #pragma unroll
        for (int b = 0; b < 4; ++b) acc[a][b] = (f32x4){0.f, 0.f, 0.f, 0.f};

    bf16x8 af[4], bf[4], afn[4], bfn[4];
    #pragma unroll
    for (int mt = 0; mt < 4; ++mt)
        af[mt] = *(const bf16x8*)(Abase + (size_t)(i0 + wio + mt * 16 + lr) * L + lg * 8);
    #pragma unroll
    for (int nt = 0; nt < 4; ++nt)
        bf[nt] = *(const bf16x8*)(VtT + (size_t)(n0 + wno + nt * 16 + lr) * L + lg * 8);

    for (int ks = 0; ks < 12; ++ks) {
        if (ks < 11) {
            const int ko = (ks + 1) * 32 + lg * 8;
            #pragma unroll
            for (int mt = 0; mt < 4; ++mt)
                afn[mt] = *(const bf16x8*)(Abase + (size_t)(i0 + wio + mt * 16 + lr) * L + ko);
            #pragma unroll
            for (int nt = 0; nt < 4; ++nt)
                bfn[nt] = *(const bf16x8*)(VtT + (size_t)(n0 + wno + nt * 16 + lr) * L + ko);
        }
        #pragma unroll
        for (int mt = 0; mt < 4; ++mt)
            #pragma unroll
            for (int nt = 0; nt < 4; ++nt)
                acc[mt][nt] = MFMA16(af[mt], bf[nt], acc[mt][nt]);
        #pragma unroll
        for (int q = 0; q < 4; ++q) { af[q] = afn[q]; bf[q] = bfn[q]; }
    }

    #pragma unroll
    for (int mt = 0; mt < 4; ++mt) {
        #pragma unroll
        for (int nt = 0; nt < 4; ++nt) {
            const int nbase = n0 + wno + nt * 16;
            const int rrow  = nbase >> 4;
            #pragma unroll
            for (int r = 0; r < 4; ++r) {
                const int i = i0 + wio + mt * 16 + lg * 4 + r;
                const size_t gidx = ((size_t)rrow * L + i) * D + h * HD + lr;
                out[gidx] = min_[gidx] + acc[mt][nt][r];
            }
        }
    }
}

// ---------------------------------------------------------------------------
// Kernel 5: FUSED FFN v4 (R13-verified: 64 rows, launch_bounds(512,4),
// 56 VGPR, reg-pipelined weights, single out pointer).
// ---------------------------------------------------------------------------
__global__ __launch_bounds__(512, 4) void k_ffn(
                      const unsigned short* __restrict__ w1gF,
                      const float2* __restrict__ c1c2,
                      const unsigned short* __restrict__ w2tF,
                      const float* __restrict__ ffb2,
                      float* out) {
    __shared__ unsigned short At[64 * 128];     // 16 KB, row-XOR swizzled
    __shared__ unsigned short hid[2][64 * 128]; // 2 x 16 KB, swizzled
    __shared__ float2 stats[64];                // (rstd, mu*rstd)
    const int tid = threadIdx.x;
    const size_t row0 = (size_t)blockIdx.x * 64;

    const int wv = tid >> 6, lane = tid & 63;
    const int lr = lane & 15, lg = lane >> 4;
    const int wm = wv >> 2, wn = wv & 3;          // 2(M:32rows) x 4(N:32cols)

    // ---- preload W1 fragments for kc=0 (overlaps A-staging) ----
    bf16x8 w1f[8], w2f[8];
    #pragma unroll
    for (int ks = 0; ks < 4; ++ks)
        #pragma unroll
        for (int nt = 0; nt < 2; ++nt) {
            const int fi = (0 * 8 + wn * 2 + nt) * 4 + ks;
            w1f[ks * 2 + nt] = *(const bf16x8*)((const char*)w1gF + fi * 1024 + lane * 16);
        }

    // ---- Stage A + inline LN3 stats: 8 threads/row x 16 f32 each ----
    {
        const int rr = tid >> 3, part = tid & 7;
        const float* src = out + (row0 + rr) * D + part * 16;
        const float4 a0 = ((const float4*)src)[0];
        const float4 a1 = ((const float4*)src)[1];
        const float4 a2 = ((const float4*)src)[2];
        const float4 a3 = ((const float4*)src)[3];
        float s  = a0.x+a0.y+a0.z+a0.w + a1.x+a1.y+a1.z+a1.w
                 + a2.x+a2.y+a2.z+a2.w + a3.x+a3.y+a3.z+a3.w;
        float sq = a0.x*a0.x+a0.y*a0.y+a0.z*a0.z+a0.w*a0.w
                 + a1.x*a1.x+a1.y*a1.y+a1.z*a1.z+a1.w*a1.w
                 + a2.x*a2.x+a2.y*a2.y+a2.z*a2.z+a2.w*a2.w
                 + a3.x*a3.x+a3.y*a3.y+a3.z*a3.z+a3.w*a3.w;
        s  += __shfl_xor(s, 1);  s  += __shfl_xor(s, 2);  s  += __shfl_xor(s, 4);
        sq += __shfl_xor(sq, 1); sq += __shfl_xor(sq, 2); sq += __shfl_xor(sq, 4);
        if (part == 0) {
            const float mean = s * (1.0f / D);
            const float rstd = rsqrtf(sq * (1.0f / D) - mean * mean + 1e-5f);
            stats[rr] = make_float2(rstd, mean * rstd);
        }
        const int xr = (rr & 7) << 4;
        char* rowp = (char*)(At + rr * 128);
        ushort4 p0, p1, p2, p3;
        p0.x = f2bf(a0.x); p0.y = f2bf(a0.y); p0.z = f2bf(a0.z); p0.w = f2bf(a0.w);
        p1.x = f2bf(a1.x); p1.y = f2bf(a1.y); p1.z = f2bf(a1.z); p1.w = f2bf(a1.w);
        p2.x = f2bf(a2.x); p2.y = f2bf(a2.y); p2.z = f2bf(a2.z); p2.w = f2bf(a2.w);
        p3.x = f2bf(a3.x); p3.y = f2bf(a3.y); p3.z = f2bf(a3.z); p3.w = f2bf(a3.w);
        const int cb = part * 32;                 // byte offset of 16 bf16
        *(ushort4*)(rowp + ((cb     ) ^ xr)) = p0;
        *(ushort4*)(rowp + ((cb +  8) ^ xr)) = p1;
        *(ushort4*)(rowp + ((cb + 16) ^ xr)) = p2;
        *(ushort4*)(rowp + ((cb + 24) ^ xr)) = p3;
    }

    // ---- preload W2 fragments for kc=0 ----
    #pragma unroll
    for (int ks = 0; ks < 4; ++ks)
        #pragma unroll
        for (int nt = 0; nt < 2; ++nt) {
            const int fi = (wn * 2 + nt) * 16 + 0 * 4 + ks;
            w2f[ks * 2 + nt] = *(const bf16x8*)((const char*)w2tF + fi * 1024 + lane * 16);
        }

    __syncthreads();

    f32x4 acc2[2][2];
    #pragma unroll
    for (int m = 0; m < 2; ++m)
        #pragma unroll
        for (int n = 0; n < 2; ++n) acc2[m][n] = (f32x4){0.f, 0.f, 0.f, 0.f};

    #pragma unroll
    for (int kc = 0; kc < 4; ++kc) {
        const int p = kc & 1;

        // ---- GEMM1-chunk ----
        {
            f32x4 acc1[2][2];
            #pragma unroll
            for (int m = 0; m < 2; ++m)
                #pragma unroll
                for (int n = 0; n < 2; ++n) acc1[m][n] = (f32x4){0.f, 0.f, 0.f, 0.f};

            #pragma unroll
            for (int ks = 0; ks < 4; ++ks) {
                bf16x8 af[2];
                #pragma unroll
                for (int mt = 0; mt < 2; ++mt) {
                    const int row = wm * 32 + mt * 16 + lr;
                    af[mt] = *(const bf16x8*)((char*)(At + row * 128) +
                              ((ks * 64 + lg * 16) ^ ((row & 7) << 4)));
                }
                #pragma unroll
                for (int mt = 0; mt < 2; ++mt)
                    #pragma unroll
                    for (int nt = 0; nt < 2; ++nt)
                        acc1[mt][nt] = MFMA16(af[mt], w1f[ks * 2 + nt], acc1[mt][nt]);
            }

            #pragma unroll
            for (int nt = 0; nt < 2; ++nt) {
                const int chl = wn * 32 + nt * 16 + lr;        // 0..127
                const float2 cc = c1c2[kc * 128 + chl];
                #pragma unroll
                for (int mt = 0; mt < 2; ++mt) {
                    #pragma unroll
                    for (int r = 0; r < 4; ++r) {
                        const int row = wm * 32 + mt * 16 + lg * 4 + r;
                        const float2 st = stats[row];
                        const float pre = st.x * acc1[mt][nt][r] - st.y * cc.x + cc.y;
                        *(unsigned short*)((char*)(hid[p] + row * 128) +
                            ((chl * 2) ^ ((row & 7) << 4))) = f2bf(fmaxf(pre, 0.f));
                    }
                }
            }
        }
        __syncthreads();

        // refill W1 for kc+1 AFTER the barrier (overlaps GEMM2)
        if (kc < 3) {
            #pragma unroll
            for (int ks = 0; ks < 4; ++ks)
                #pragma unroll
                for (int nt = 0; nt < 2; ++nt) {
                    const int fi = ((kc + 1) * 8 + wn * 2 + nt) * 4 + ks;
                    w1f[ks * 2 + nt] = *(const bf16x8*)((const char*)w1gF + fi * 1024 + lane * 16);
                }
        }

        // ---- GEMM2-chunk ----
        {
            #pragma unroll
            for (int ks = 0; ks < 4; ++ks) {
                bf16x8 hf[2];
                #pragma unroll
                for (int mt = 0; mt < 2; ++mt) {
                    const int row = wm * 32 + mt * 16 + lr;
                    hf[mt] = *(const bf16x8*)((char*)(hid[p] + row * 128) +
                              ((ks * 64 + lg * 16) ^ ((row & 7) << 4)));
                }
                #pragma unroll
                for (int mt = 0; mt < 2; ++mt)
                    #pragma unroll
                    for (int nt = 0; nt < 2; ++nt)
                        acc2[mt][nt] = MFMA16(hf[mt], w2f[ks * 2 + nt], acc2[mt][nt]);
            }
        }

        // refill W2 for kc+1 (overlaps next GEMM1)
        if (kc < 3) {
            #pragma unroll
            for (int ks = 0; ks < 4; ++ks)
                #pragma unroll
                for (int nt = 0; nt < 2; ++nt) {
                    const int fi = (wn * 2 + nt) * 16 + (kc + 1) * 4 + ks;
                    w2f[ks * 2 + nt] = *(const bf16x8*)((const char*)w2tF + fi * 1024 + lane * 16);
                }
        }
    }

    // ---- epilogue: out += acc2 + ffb2 ----
    #pragma unroll
    for (int nt = 0; nt < 2; ++nt) {
        const int ch = wn * 32 + nt * 16 + lr;
        const float bb = ffb2[ch];
        #pragma unroll
        for (int mt = 0; mt < 2; ++mt) {
            #pragma unroll
            for (int r = 0; r < 4; ++r) {
                const size_t gi = (row0 + wm * 32 + mt * 16 + lg * 4 + r) * (size_t)D + ch;
                out[gi] = out[gi] + acc2[mt][nt][r] + bb;
            }
        }
    }
}

// ---------------------------------------------------------------------------
extern "C" void kernel_launch(void* const* d_in, const int* in_sizes, int n_in,
                              void* d_out, int out_size, void* d_ws, size_t ws_size,
                              hipStream_t stream) {
    const float* x     = (const float*)d_in[0];
    const float* m     = (const float*)d_in[1];
    const float* ln1_g = (const float*)d_in[2];
    const float* ln1_b = (const float*)d_in[3];
    const float* ln2_g = (const float*)d_in[4];
    const float* ln2_b = (const float*)d_in[5];
    const float* ln3_g = (const float*)d_in[6];
    const float* ln3_b = (const float*)d_in[7];
    const float* w1    = (const float*)d_in[8];
    const float* b1    = (const float*)d_in[9];
    const float* w2    = (const float*)d_in[10];
    const float* b2    = (const float*)d_in[11];
    const float* ffw1  = (const float*)d_in[12];
    const float* ffb1  = (const float*)d_in[13];
    const float* ffw2  = (const float*)d_in[14];
    const float* ffb2  = (const float*)d_in[15];

    float* out = (float*)d_out;

    char* wsp = (char*)d_ws;
    float*          logits = (float*)wsp;              wsp += (size_t)L*L*NH*4;   // 4.72 MB
    unsigned short* attnT  = (unsigned short*)wsp;     wsp += (size_t)NH*L*L*2;   // 2.36 MB
    unsigned short* VtT    = (unsigned short*)wsp;     wsp += (size_t)R*HD*L*2;   // 3.15 MB
    unsigned short* w1gF   = (unsigned short*)wsp;     wsp += (size_t)FF*D*2;     // 128 KB
    unsigned short* w2tF   = (unsigned short*)wsp;     wsp += (size_t)D*FF*2;     // 128 KB
    unsigned short* w1p    = (unsigned short*)wsp;     wsp += (size_t)16*D*2;     // 4 KB
    unsigned short* w2p    = (unsigned short*)wsp;     wsp += (size_t)16*D*2;     // 4 KB
    float2*         c1c2   = (float2*)wsp;             wsp += (size_t)FF*8;       // 4 KB

    k_prep<<<(FF * D) / 256, 256, 0, stream>>>(w1, w2, ffw1, ffw2,
                                               ln3_g, ln3_b, ffb1,
                                               w1p, w2p, w1gF, w2tF, c1c2);

    // upper-triangle pair count: 384*385/2 = 73920 -> 1155 blocks of 64
    k_pair_logits<<<1155, 256, 0, stream>>>(x, ln1_g, ln1_b, w1p, b1, logits);
    k_softmax<<<(L * NH) / 4, 256, 0, stream>>>(logits, attnT);

    dim3 g3(R, L / 128);
    k_values<<<g3, 256, 0, stream>>>(m, ln2_g, ln2_b, w2p, b2, VtT);

    // 768 blocks flattened 1-D (3 i-tiles x 32 n-tiles x 8 heads)
    k_attn_out<<<768, 256, 0, stream>>>(attnT, VtT, m, out);

    k_ffn<<<(R * L) / 64, 512, 0, stream>>>(w1gF, c1c2, w2tF, ffb2, out);
}

// Round 16
// 153.636 us; speedup vs baseline: 2.0452x; 1.3568x over previous
//
#include <hip/hip_runtime.h>

typedef __attribute__((ext_vector_type(8))) short bf16x8;
typedef __attribute__((ext_vector_type(4))) float f32x4;

constexpr int L  = 384;
constexpr int R  = 256;
constexpr int D  = 128;
constexpr int NH = 8;
constexpr int HD = 16;
constexpr int FF = 512;

#define MFMA16(a, b, c) __builtin_amdgcn_mfma_f32_16x16x32_bf16((a), (b), (c), 0, 0, 0)

__device__ inline unsigned short f2bf(float f) {
    unsigned u = __builtin_bit_cast(unsigned, f);
    u += 0x7fffu + ((u >> 16) & 1u);          // round-to-nearest-even
    return (unsigned short)(u >> 16);
}
__device__ inline float bf2f(unsigned short h) {
    unsigned u = ((unsigned)h) << 16;
    return __builtin_bit_cast(float, u);
}

// triangular row from linear upper-tri index q (i<=j), L=384: off(i)=i*(769-i)/2
__device__ inline int tri_row(int q) {
    int i = (int)((769.0f - sqrtf((float)(591361 - 8 * q))) * 0.5f);
    while ((i + 1) * (769 - (i + 1)) / 2 <= q) ++i;
    while (i * (769 - i) / 2 > q) --i;
    return i;
}

// ---------------------------------------------------------------------------
// Prep: attn weights (w1p/w2p), LN3-fold constants, FRAGMENTIZED FFN weights
// ---------------------------------------------------------------------------
__global__ void k_prep(const float* __restrict__ w1,
                       const float* __restrict__ w2,
                       const float* __restrict__ ffw1,
                       const float* __restrict__ ffw2,
                       const float* __restrict__ g3,
                       const float* __restrict__ b3,
                       const float* __restrict__ ffb1,
                       unsigned short* __restrict__ w1p,
                       unsigned short* __restrict__ w2p,
                       unsigned short* __restrict__ w1gF,
                       unsigned short* __restrict__ w2tF,
                       float2* __restrict__ c1c2) {
    const int idx = blockIdx.x * 256 + threadIdx.x;   // 65536 threads
    {
        const int fi = idx >> 9, rem = idx & 511, l = rem >> 3, e = rem & 7;
        const int lr2 = l & 15, lg2 = l >> 4;
        const int n = fi >> 2, ks = fi & 3;
        const int ch = n * 16 + lr2, k = ks * 32 + lg2 * 8 + e;
        w1gF[idx] = f2bf(g3[k] * ffw1[(size_t)k * FF + ch]);
    }
    {
        const int fi = idx >> 9, rem = idx & 511, l = rem >> 3, e = rem & 7;
        const int lr2 = l & 15, lg2 = l >> 4;
        const int n = fi >> 4, Ks = fi & 15;
        const int ch = n * 16 + lr2, k = Ks * 32 + lg2 * 8 + e;
        w2tF[idx] = f2bf(ffw2[(size_t)k * D + ch]);
    }
    if (idx < 16 * D) {
        const int n = idx >> 7, k = idx & 127;
        w1p[idx] = (n < NH) ? f2bf(w1[(size_t)k * NH + n]) : (unsigned short)0;
        w2p[idx] = f2bf(w2[(size_t)k * HD + n]);
    }
    if (blockIdx.x < 2) {
        const int n = blockIdx.x * 256 + threadIdx.x;   // 0..511
        float c1 = 0.f, c2 = 0.f;
        for (int k = 0; k < D; ++k) {
            const float w = ffw1[(size_t)k * FF + n];
            c1 += g3[k] * w;
            c2 += b3[k] * w;
        }
        c1c2[n] = make_float2(c1, c2 + ffb1[n]);
    }
}

// ---------------------------------------------------------------------------
// Kernel 1: symmetrize + LN1 + logits via MFMA, upper triangle only
// ---------------------------------------------------------------------------
__global__ void k_pair_logits(const float* __restrict__ x,
                              const float* __restrict__ g,
                              const float* __restrict__ bt,
                              const unsigned short* __restrict__ w1p,
                              const float* __restrict__ b1,
                              float* __restrict__ logits) {
    __shared__ unsigned short nrm[64][136];
    __shared__ int ij[64];
    const int tid = threadIdx.x;
    const int q0 = blockIdx.x * 64;

    {
        const int pr = tid >> 2, part = tid & 3;
        const int q = q0 + pr;
        const int i = tri_row(q);
        const int j = i + (q - i * (769 - i) / 2);
        if (part == 0) ij[pr] = (i << 16) | j;
        const float* xa = x + ((size_t)i * L + j) * D + part * 32;
        const float* xb = x + ((size_t)j * L + i) * D + part * 32;
        float v[32];
        float s = 0.f, sq = 0.f;
        #pragma unroll
        for (int q8 = 0; q8 < 8; ++q8) {
            const float4 a = ((const float4*)xa)[q8];
            const float4 b = ((const float4*)xb)[q8];
            const float t0 = 0.5f * (a.x + b.x), t1 = 0.5f * (a.y + b.y);
            const float t2 = 0.5f * (a.z + b.z), t3 = 0.5f * (a.w + b.w);
            v[q8*4+0] = t0; v[q8*4+1] = t1; v[q8*4+2] = t2; v[q8*4+3] = t3;
            s  += t0 + t1 + t2 + t3;
            sq += t0*t0 + t1*t1 + t2*t2 + t3*t3;
        }
        s  += __shfl_xor(s, 1);  s  += __shfl_xor(s, 2);
        sq += __shfl_xor(sq, 1); sq += __shfl_xor(sq, 2);
        const float mean = s * (1.0f / D);
        const float rstd = rsqrtf(sq * (1.0f / D) - mean * mean + 1e-5f);
        #pragma unroll
        for (int q8 = 0; q8 < 8; ++q8) {
            const int c = part * 32 + q8 * 4;
            ushort4 pk;
            pk.x = f2bf((v[q8*4+0] - mean) * rstd * g[c+0] + bt[c+0]);
            pk.y = f2bf((v[q8*4+1] - mean) * rstd * g[c+1] + bt[c+1]);
            pk.z = f2bf((v[q8*4+2] - mean) * rstd * g[c+2] + bt[c+2]);
            pk.w = f2bf((v[q8*4+3] - mean) * rstd * g[c+3] + bt[c+3]);
            *(ushort4*)(&nrm[pr][c]) = pk;
        }
    }
    __syncthreads();

    {
        const int wv = tid >> 6, lane = tid & 63;
        const int lr = lane & 15, lg = lane >> 4;
        f32x4 acc = {0.f, 0.f, 0.f, 0.f};
        #pragma unroll
        for (int ks = 0; ks < 4; ++ks) {
            bf16x8 a = *(const bf16x8*)(&nrm[wv * 16 + lr][ks * 32 + lg * 8]);
            bf16x8 b = *(const bf16x8*)(w1p + (size_t)lr * D + ks * 32 + lg * 8);
            acc = MFMA16(a, b, acc);
        }
        if (lr < NH) {
            #pragma unroll
            for (int r = 0; r < 4; ++r) {
                const int pl = wv * 16 + lg * 4 + r;
                const int pij = ij[pl];
                const int pi = pij >> 16, pj = pij & 0xffff;
                const float val = acc[r] + b1[lr];
                logits[((size_t)pi * L + pj) * NH + lr] = val;
                logits[((size_t)pj * L + pi) * NH + lr] = val;
            }
        }
    }
}

// ---------------------------------------------------------------------------
// Kernel 2: softmax over j for each (i,h); logits f32 -> attnT bf16 [h][i][j]
// ---------------------------------------------------------------------------
__global__ void k_softmax(const float* __restrict__ logits,
                          unsigned short* __restrict__ attnT) {
    const int wave = blockIdx.x * 4 + (threadIdx.x >> 6);
    const int lane = threadIdx.x & 63;
    const int i = wave >> 3, h = wave & 7;

    float v[6];
    float mx = -1e30f;
    #pragma unroll
    for (int t = 0; t < 6; ++t) {
        const int j = lane + t * 64;
        v[t] = logits[((size_t)i * L + j) * NH + h];
        mx = fmaxf(mx, v[t]);
    }
    #pragma unroll
    for (int msk = 32; msk; msk >>= 1) mx = fmaxf(mx, __shfl_xor(mx, msk));

    float s = 0.0f;
    #pragma unroll
    for (int t = 0; t < 6; ++t) { v[t] = __expf(v[t] - mx); s += v[t]; }
    #pragma unroll
    for (int msk = 32; msk; msk >>= 1) s += __shfl_xor(s, msk);
    const float inv = 1.0f / s;

    #pragma unroll
    for (int t = 0; t < 6; ++t) {
        const int j = lane + t * 64;
        attnT[((size_t)h * L + i) * L + j] = f2bf(v[t] * inv);
    }
}

// ---------------------------------------------------------------------------
// Kernel 3: values = LN2(m) @ w2 + b2 -> VtT bf16 [n = r*16+d][j]
// ---------------------------------------------------------------------------
__global__ void k_values(const float* __restrict__ min_,
                         const float* __restrict__ g,
                         const float* __restrict__ bt,
                         const unsigned short* __restrict__ w2p,
                         const float* __restrict__ b2,
                         unsigned short* __restrict__ VtT) {
    __shared__ unsigned short nrm[128][136];
    const int tid = threadIdx.x;
    const int r  = blockIdx.x;
    const int j0 = blockIdx.y * 128;

    #pragma unroll
    for (int half = 0; half < 2; ++half) {
        const int row  = half * 64 + (tid >> 2);
        const int part = tid & 3;
        const float* src = min_ + ((size_t)r * L + j0 + row) * D + part * 32;
        float v[32];
        float s = 0.f, sq = 0.f;
        #pragma unroll
        for (int q = 0; q < 8; ++q) {
            const float4 a = ((const float4*)src)[q];
            v[q*4+0] = a.x; v[q*4+1] = a.y; v[q*4+2] = a.z; v[q*4+3] = a.w;
            s  += a.x + a.y + a.z + a.w;
            sq += a.x*a.x + a.y*a.y + a.z*a.z + a.w*a.w;
        }
        s  += __shfl_xor(s, 1);  s  += __shfl_xor(s, 2);
        sq += __shfl_xor(sq, 1); sq += __shfl_xor(sq, 2);
        const float mean = s * (1.0f / D);
        const float rstd = rsqrtf(sq * (1.0f / D) - mean * mean + 1e-5f);
        #pragma unroll
        for (int q = 0; q < 8; ++q) {
            const int c = part * 32 + q * 4;
            ushort4 pk;
            pk.x = f2bf((v[q*4+0] - mean) * rstd * g[c+0] + bt[c+0]);
            pk.y = f2bf((v[q*4+1] - mean) * rstd * g[c+1] + bt[c+1]);
            pk.z = f2bf((v[q*4+2] - mean) * rstd * g[c+2] + bt[c+2]);
            pk.w = f2bf((v[q*4+3] - mean) * rstd * g[c+3] + bt[c+3]);
            *(ushort4*)(&nrm[row][c]) = pk;
        }
    }
    __syncthreads();

    {
        const int wv = tid >> 6, lane = tid & 63;
        const int lr = lane & 15, lg = lane >> 4;
        f32x4 acc[2];
        acc[0] = (f32x4){0.f, 0.f, 0.f, 0.f};
        acc[1] = (f32x4){0.f, 0.f, 0.f, 0.f};
        #pragma unroll
        for (int ks = 0; ks < 4; ++ks) {
            bf16x8 b = *(const bf16x8*)(w2p + (size_t)lr * D + ks * 32 + lg * 8);
            #pragma unroll
            for (int mt = 0; mt < 2; ++mt) {
                bf16x8 a = *(const bf16x8*)(&nrm[wv * 32 + mt * 16 + lr][ks * 32 + lg * 8]);
                acc[mt] = MFMA16(a, b, acc[mt]);
            }
        }
        const float bb = b2[lr];
        #pragma unroll
        for (int mt = 0; mt < 2; ++mt) {
            ushort4 pk;
            pk.x = f2bf(acc[mt][0] + bb);
            pk.y = f2bf(acc[mt][1] + bb);
            pk.z = f2bf(acc[mt][2] + bb);
            pk.w = f2bf(acc[mt][3] + bb);
            *(ushort4*)(VtT + (size_t)(r * HD + lr) * L + j0 + wv * 32 + mt * 16 + lg * 4) = pk;
        }
    }
}

// ---------------------------------------------------------------------------
// Kernel 4: einsum via MFMA with 1-deep register double-buffered fragment
// loads (R13-verified dim3 form). Epilogue: out = m + acc (f32).
// ---------------------------------------------------------------------------
__global__ void k_attn_out(const unsigned short* __restrict__ attnT,
                           const unsigned short* __restrict__ VtT,
                           const float* __restrict__ min_,
                           float* __restrict__ out) {
    const int h  = blockIdx.z;
    const int i0 = blockIdx.x * 128;
    const int n0 = blockIdx.y * 128;
    const int tid = threadIdx.x, wv = tid >> 6, lane = tid & 63;
    const int lr = lane & 15, lg = lane >> 4;
    const int wio = (wv >> 1) * 64, wno = (wv & 1) * 64;
    const unsigned short* Abase = attnT + (size_t)h * L * L;

    f32x4 acc[4][4];
    #pragma unroll
    for (int a = 0; a < 4; ++a)
        #pragma unroll
        for (int b = 0; b < 4; ++b) acc[a][b] = (f32x4){0.f, 0.f, 0.f, 0.f};

    bf16x8 af[4], bf[4], afn[4], bfn[4];
    #pragma unroll
    for (int mt = 0; mt < 4; ++mt)
        af[mt] = *(const bf16x8*)(Abase + (size_t)(i0 + wio + mt * 16 + lr) * L + lg * 8);
    #pragma unroll
    for (int nt = 0; nt < 4; ++nt)
        bf[nt] = *(const bf16x8*)(VtT + (size_t)(n0 + wno + nt * 16 + lr) * L + lg * 8);

    for (int ks = 0; ks < 12; ++ks) {
        if (ks < 11) {
            const int ko = (ks + 1) * 32 + lg * 8;
            #pragma unroll
            for (int mt = 0; mt < 4; ++mt)
                afn[mt] = *(const bf16x8*)(Abase + (size_t)(i0 + wio + mt * 16 + lr) * L + ko);
            #pragma unroll
            for (int nt = 0; nt < 4; ++nt)
                bfn[nt] = *(const bf16x8*)(VtT + (size_t)(n0 + wno + nt * 16 + lr) * L + ko);
        }
        #pragma unroll
        for (int mt = 0; mt < 4; ++mt)
            #pragma unroll
            for (int nt = 0; nt < 4; ++nt)
                acc[mt][nt] = MFMA16(af[mt], bf[nt], acc[mt][nt]);
        #pragma unroll
        for (int q = 0; q < 4; ++q) { af[q] = afn[q]; bf[q] = bfn[q]; }
    }

    #pragma unroll
    for (int mt = 0; mt < 4; ++mt) {
        #pragma unroll
        for (int nt = 0; nt < 4; ++nt) {
            const int nbase = n0 + wno + nt * 16;
            const int rrow  = nbase >> 4;
            #pragma unroll
            for (int r = 0; r < 4; ++r) {
                const int i = i0 + wio + mt * 16 + lg * 4 + r;
                const size_t gidx = ((size_t)rrow * L + i) * D + h * HD + lr;
                out[gidx] = min_[gidx] + acc[mt][nt][r];
            }
        }
    }
}

// ---------------------------------------------------------------------------
// Kernel 5: FUSED FFN v6 — R13 structure + LDS-residual epilogue (no global
// RMW read; residual taken from At bf16, R11-verified numerics).
// ---------------------------------------------------------------------------
__global__ __launch_bounds__(512, 4) void k_ffn(
                      const unsigned short* __restrict__ w1gF,
                      const float2* __restrict__ c1c2,
                      const unsigned short* __restrict__ w2tF,
                      const float* __restrict__ ffb2,
                      float* out) {
    __shared__ unsigned short At[64 * 128];     // 16 KB, row-XOR swizzled
    __shared__ unsigned short hid[2][64 * 128]; // 2 x 16 KB, swizzled
    __shared__ float2 stats[64];                // (rstd, mu*rstd)
    const int tid = threadIdx.x;
    const size_t row0 = (size_t)blockIdx.x * 64;

    const int wv = tid >> 6, lane = tid & 63;
    const int lr = lane & 15, lg = lane >> 4;
    const int wm = wv >> 2, wn = wv & 3;          // 2(M:32rows) x 4(N:32cols)

    // ---- preload W1 fragments for kc=0 (overlaps A-staging) ----
    bf16x8 w1f[8], w2f[8];
    #pragma unroll
    for (int ks = 0; ks < 4; ++ks)
        #pragma unroll
        for (int nt = 0; nt < 2; ++nt) {
            const int fi = (0 * 8 + wn * 2 + nt) * 4 + ks;
            w1f[ks * 2 + nt] = *(const bf16x8*)((const char*)w1gF + fi * 1024 + lane * 16);
        }

    // ---- Stage A + inline LN3 stats: 8 threads/row x 16 f32 each ----
    {
        const int rr = tid >> 3, part = tid & 7;
        const float* src = out + (row0 + rr) * D + part * 16;
        const float4 a0 = ((const float4*)src)[0];
        const float4 a1 = ((const float4*)src)[1];
        const float4 a2 = ((const float4*)src)[2];
        const float4 a3 = ((const float4*)src)[3];
        float s  = a0.x+a0.y+a0.z+a0.w + a1.x+a1.y+a1.z+a1.w
                 + a2.x+a2.y+a2.z+a2.w + a3.x+a3.y+a3.z+a3.w;
        float sq = a0.x*a0.x+a0.y*a0.y+a0.z*a0.z+a0.w*a0.w
                 + a1.x*a1.x+a1.y*a1.y+a1.z*a1.z+a1.w*a1.w
                 + a2.x*a2.x+a2.y*a2.y+a2.z*a2.z+a2.w*a2.w
                 + a3.x*a3.x+a3.y*a3.y+a3.z*a3.z+a3.w*a3.w;
        s  += __shfl_xor(s, 1);  s  += __shfl_xor(s, 2);  s  += __shfl_xor(s, 4);
        sq += __shfl_xor(sq, 1); sq += __shfl_xor(sq, 2); sq += __shfl_xor(sq, 4);
        if (part == 0) {
            const float mean = s * (1.0f / D);
            const float rstd = rsqrtf(sq * (1.0f / D) - mean * mean + 1e-5f);
            stats[rr] = make_float2(rstd, mean * rstd);
        }
        const int xr = (rr & 7) << 4;
        char* rowp = (char*)(At + rr * 128);
        ushort4 p0, p1, p2, p3;
        p0.x = f2bf(a0.x); p0.y = f2bf(a0.y); p0.z = f2bf(a0.z); p0.w = f2bf(a0.w);
        p1.x = f2bf(a1.x); p1.y = f2bf(a1.y); p1.z = f2bf(a1.z); p1.w = f2bf(a1.w);
        p2.x = f2bf(a2.x); p2.y = f2bf(a2.y); p2.z = f2bf(a2.z); p2.w = f2bf(a2.w);
        p3.x = f2bf(a3.x); p3.y = f2bf(a3.y); p3.z = f2bf(a3.z); p3.w = f2bf(a3.w);
        const int cb = part * 32;                 // byte offset of 16 bf16
        *(ushort4*)(rowp + ((cb     ) ^ xr)) = p0;
        *(ushort4*)(rowp + ((cb +  8) ^ xr)) = p1;
        *(ushort4*)(rowp + ((cb + 16) ^ xr)) = p2;
        *(ushort4*)(rowp + ((cb + 24) ^ xr)) = p3;
    }

    // ---- preload W2 fragments for kc=0 ----
    #pragma unroll
    for (int ks = 0; ks < 4; ++ks)
        #pragma unroll
        for (int nt = 0; nt < 2; ++nt) {
            const int fi = (wn * 2 + nt) * 16 + 0 * 4 + ks;
            w2f[ks * 2 + nt] = *(const bf16x8*)((const char*)w2tF + fi * 1024 + lane * 16);
        }

    __syncthreads();

    f32x4 acc2[2][2];
    #pragma unroll
    for (int m = 0; m < 2; ++m)
        #pragma unroll
        for (int n = 0; n < 2; ++n) acc2[m][n] = (f32x4){0.f, 0.f, 0.f, 0.f};

    #pragma unroll
    for (int kc = 0; kc < 4; ++kc) {
        const int p = kc & 1;

        // ---- GEMM1-chunk ----
        {
            f32x4 acc1[2][2];
            #pragma unroll
            for (int m = 0; m < 2; ++m)
                #pragma unroll
                for (int n = 0; n < 2; ++n) acc1[m][n] = (f32x4){0.f, 0.f, 0.f, 0.f};

            #pragma unroll
            for (int ks = 0; ks < 4; ++ks) {
                bf16x8 af[2];
                #pragma unroll
                for (int mt = 0; mt < 2; ++mt) {
                    const int row = wm * 32 + mt * 16 + lr;
                    af[mt] = *(const bf16x8*)((char*)(At + row * 128) +
                              ((ks * 64 + lg * 16) ^ ((row & 7) << 4)));
                }
                #pragma unroll
                for (int mt = 0; mt < 2; ++mt)
                    #pragma unroll
                    for (int nt = 0; nt < 2; ++nt)
                        acc1[mt][nt] = MFMA16(af[mt], w1f[ks * 2 + nt], acc1[mt][nt]);
            }

            #pragma unroll
            for (int nt = 0; nt < 2; ++nt) {
                const int chl = wn * 32 + nt * 16 + lr;        // 0..127
                const float2 cc = c1c2[kc * 128 + chl];
                #pragma unroll
                for (int mt = 0; mt < 2; ++mt) {
                    #pragma unroll
                    for (int r = 0; r < 4; ++r) {
                        const int row = wm * 32 + mt * 16 + lg * 4 + r;
                        const float2 st = stats[row];
                        const float pre = st.x * acc1[mt][nt][r] - st.y * cc.x + cc.y;
                        *(unsigned short*)((char*)(hid[p] + row * 128) +
                            ((chl * 2) ^ ((row & 7) << 4))) = f2bf(fmaxf(pre, 0.f));
                    }
                }
            }
        }
        __syncthreads();

        // refill W1 for kc+1 AFTER the barrier (overlaps GEMM2)
        if (kc < 3) {
            #pragma unroll
            for (int ks = 0; ks < 4; ++ks)
                #pragma unroll
                for (int nt = 0; nt < 2; ++nt) {
                    const int fi = ((kc + 1) * 8 + wn * 2 + nt) * 4 + ks;
                    w1f[ks * 2 + nt] = *(const bf16x8*)((const char*)w1gF + fi * 1024 + lane * 16);
                }
        }

        // ---- GEMM2-chunk ----
        {
            #pragma unroll
            for (int ks = 0; ks < 4; ++ks) {
                bf16x8 hf[2];
                #pragma unroll
                for (int mt = 0; mt < 2; ++mt) {
                    const int row = wm * 32 + mt * 16 + lr;
                    hf[mt] = *(const bf16x8*)((char*)(hid[p] + row * 128) +
                              ((ks * 64 + lg * 16) ^ ((row & 7) << 4)));
                }
                #pragma unroll
                for (int mt = 0; mt < 2; ++mt)
                    #pragma unroll
                    for (int nt = 0; nt < 2; ++nt)
                        acc2[mt][nt] = MFMA16(hf[mt], w2f[ks * 2 + nt], acc2[mt][nt]);
            }
        }

        // refill W2 for kc+1 (overlaps next GEMM1)
        if (kc < 3) {
            #pragma unroll
            for (int ks = 0; ks < 4; ++ks)
                #pragma unroll
                for (int nt = 0; nt < 2; ++nt) {
                    const int fi = (wn * 2 + nt) * 16 + (kc + 1) * 4 + ks;
                    w2f[ks * 2 + nt] = *(const bf16x8*)((const char*)w2tF + fi * 1024 + lane * 16);
                }
        }
    }

    // ---- epilogue: out = bf2f(At) + acc2 + ffb2 (pure store, no RMW) ----
    #pragma unroll
    for (int nt = 0; nt < 2; ++nt) {
        const int ch = wn * 32 + nt * 16 + lr;
        const float bb = ffb2[ch];
        #pragma unroll
        for (int mt = 0; mt < 2; ++mt) {
            #pragma unroll
            for (int r = 0; r < 4; ++r) {
                const int row = wm * 32 + mt * 16 + lg * 4 + r;
                const float resid = bf2f(*(const unsigned short*)((char*)(At + row * 128) +
                                     ((ch * 2) ^ ((row & 7) << 4))));
                out[(row0 + row) * (size_t)D + ch] = resid + acc2[mt][nt][r] + bb;
            }
        }
    }
}

// ---------------------------------------------------------------------------
extern "C" void kernel_launch(void* const* d_in, const int* in_sizes, int n_in,
                              void* d_out, int out_size, void* d_ws, size_t ws_size,
                              hipStream_t stream) {
    const float* x     = (const float*)d_in[0];
    const float* m     = (const float*)d_in[1];
    const float* ln1_g = (const float*)d_in[2];
    const float* ln1_b = (const float*)d_in[3];
    const float* ln2_g = (const float*)d_in[4];
    const float* ln2_b = (const float*)d_in[5];
    const float* ln3_g = (const float*)d_in[6];
    const float* ln3_b = (const float*)d_in[7];
    const float* w1    = (const float*)d_in[8];
    const float* b1    = (const float*)d_in[9];
    const float* w2    = (const float*)d_in[10];
    const float* b2    = (const float*)d_in[11];
    const float* ffw1  = (const float*)d_in[12];
    const float* ffb1  = (const float*)d_in[13];
    const float* ffw2  = (const float*)d_in[14];
    const float* ffb2  = (const float*)d_in[15];

    float* out = (float*)d_out;

    char* wsp = (char*)d_ws;
    float*          logits = (float*)wsp;              wsp += (size_t)L*L*NH*4;   // 4.72 MB
    unsigned short* attnT  = (unsigned short*)wsp;     wsp += (size_t)NH*L*L*2;   // 2.36 MB
    unsigned short* VtT    = (unsigned short*)wsp;     wsp += (size_t)R*HD*L*2;   // 3.15 MB
    unsigned short* w1gF   = (unsigned short*)wsp;     wsp += (size_t)FF*D*2;     // 128 KB
    unsigned short* w2tF   = (unsigned short*)wsp;     wsp += (size_t)D*FF*2;     // 128 KB
    unsigned short* w1p    = (unsigned short*)wsp;     wsp += (size_t)16*D*2;     // 4 KB
    unsigned short* w2p    = (unsigned short*)wsp;     wsp += (size_t)16*D*2;     // 4 KB
    float2*         c1c2   = (float2*)wsp;             wsp += (size_t)FF*8;       // 4 KB

    k_prep<<<(FF * D) / 256, 256, 0, stream>>>(w1, w2, ffw1, ffw2,
                                               ln3_g, ln3_b, ffb1,
                                               w1p, w2p, w1gF, w2tF, c1c2);

    // upper-triangle pair count: 384*385/2 = 73920 -> 1155 blocks of 64
    k_pair_logits<<<1155, 256, 0, stream>>>(x, ln1_g, ln1_b, w1p, b1, logits);
    k_softmax<<<(L * NH) / 4, 256, 0, stream>>>(logits, attnT);

    dim3 g3(R, L / 128);
    k_values<<<g3, 256, 0, stream>>>(m, ln2_g, ln2_b, w2p, b2, VtT);

    dim3 g4(L / 128, (R * HD) / 128, NH);
    k_attn_out<<<g4, 256, 0, stream>>>(attnT, VtT, m, out);

    k_ffn<<<(R * L) / 64, 512, 0, stream>>>(w1gF, c1c2, w2tF, ffb2, out);
}

// Round 17
// 148.124 us; speedup vs baseline: 2.1213x; 1.0372x over previous
//
#include <hip/hip_runtime.h>

typedef __attribute__((ext_vector_type(8))) short bf16x8;
typedef __attribute__((ext_vector_type(4))) float f32x4;

constexpr int L  = 384;
constexpr int R  = 256;
constexpr int D  = 128;
constexpr int NH = 8;
constexpr int HD = 16;
constexpr int FF = 512;

#define MFMA16(a, b, c) __builtin_amdgcn_mfma_f32_16x16x32_bf16((a), (b), (c), 0, 0, 0)

__device__ inline unsigned short f2bf(float f) {
    unsigned u = __builtin_bit_cast(unsigned, f);
    u += 0x7fffu + ((u >> 16) & 1u);          // round-to-nearest-even
    return (unsigned short)(u >> 16);
}
__device__ inline float bf2f(unsigned short h) {
    unsigned u = ((unsigned)h) << 16;
    return __builtin_bit_cast(float, u);
}

// triangular row from linear upper-tri index q (i<=j), L=384: off(i)=i*(769-i)/2
__device__ inline int tri_row(int q) {
    int i = (int)((769.0f - sqrtf((float)(591361 - 8 * q))) * 0.5f);
    while ((i + 1) * (769 - (i + 1)) / 2 <= q) ++i;
    while (i * (769 - i) / 2 > q) --i;
    return i;
}

// ---------------------------------------------------------------------------
// Prep: attn weights (w1p/w2p), LN3-fold constants, FRAGMENTIZED FFN weights
// ---------------------------------------------------------------------------
__global__ void k_prep(const float* __restrict__ w1,
                       const float* __restrict__ w2,
                       const float* __restrict__ ffw1,
                       const float* __restrict__ ffw2,
                       const float* __restrict__ g3,
                       const float* __restrict__ b3,
                       const float* __restrict__ ffb1,
                       unsigned short* __restrict__ w1p,
                       unsigned short* __restrict__ w2p,
                       unsigned short* __restrict__ w1gF,
                       unsigned short* __restrict__ w2tF,
                       float2* __restrict__ c1c2) {
    const int idx = blockIdx.x * 256 + threadIdx.x;   // 65536 threads
    {
        const int fi = idx >> 9, rem = idx & 511, l = rem >> 3, e = rem & 7;
        const int lr2 = l & 15, lg2 = l >> 4;
        const int n = fi >> 2, ks = fi & 3;
        const int ch = n * 16 + lr2, k = ks * 32 + lg2 * 8 + e;
        w1gF[idx] = f2bf(g3[k] * ffw1[(size_t)k * FF + ch]);
    }
    {
        const int fi = idx >> 9, rem = idx & 511, l = rem >> 3, e = rem & 7;
        const int lr2 = l & 15, lg2 = l >> 4;
        const int n = fi >> 4, Ks = fi & 15;
        const int ch = n * 16 + lr2, k = Ks * 32 + lg2 * 8 + e;
        w2tF[idx] = f2bf(ffw2[(size_t)k * D + ch]);
    }
    if (idx < 16 * D) {
        const int n = idx >> 7, k = idx & 127;
        w1p[idx] = (n < NH) ? f2bf(w1[(size_t)k * NH + n]) : (unsigned short)0;
        w2p[idx] = f2bf(w2[(size_t)k * HD + n]);
    }
    if (blockIdx.x < 2) {
        const int n = blockIdx.x * 256 + threadIdx.x;   // 0..511
        float c1 = 0.f, c2 = 0.f;
        for (int k = 0; k < D; ++k) {
            const float w = ffw1[(size_t)k * FF + n];
            c1 += g3[k] * w;
            c2 += b3[k] * w;
        }
        c1c2[n] = make_float2(c1, c2 + ffb1[n]);
    }
}

// ---------------------------------------------------------------------------
// Kernel 1: symmetrize + LN1 + logits via MFMA, upper triangle only
// ---------------------------------------------------------------------------
__global__ void k_pair_logits(const float* __restrict__ x,
                              const float* __restrict__ g,
                              const float* __restrict__ bt,
                              const unsigned short* __restrict__ w1p,
                              const float* __restrict__ b1,
                              float* __restrict__ logits) {
    __shared__ unsigned short nrm[64][136];
    __shared__ int ij[64];
    const int tid = threadIdx.x;
    const int q0 = blockIdx.x * 64;

    {
        const int pr = tid >> 2, part = tid & 3;
        const int q = q0 + pr;
        const int i = tri_row(q);
        const int j = i + (q - i * (769 - i) / 2);
        if (part == 0) ij[pr] = (i << 16) | j;
        const float* xa = x + ((size_t)i * L + j) * D + part * 32;
        const float* xb = x + ((size_t)j * L + i) * D + part * 32;
        float v[32];
        float s = 0.f, sq = 0.f;
        #pragma unroll
        for (int q8 = 0; q8 < 8; ++q8) {
            const float4 a = ((const float4*)xa)[q8];
            const float4 b = ((const float4*)xb)[q8];
            const float t0 = 0.5f * (a.x + b.x), t1 = 0.5f * (a.y + b.y);
            const float t2 = 0.5f * (a.z + b.z), t3 = 0.5f * (a.w + b.w);
            v[q8*4+0] = t0; v[q8*4+1] = t1; v[q8*4+2] = t2; v[q8*4+3] = t3;
            s  += t0 + t1 + t2 + t3;
            sq += t0*t0 + t1*t1 + t2*t2 + t3*t3;
        }
        s  += __shfl_xor(s, 1);  s  += __shfl_xor(s, 2);
        sq += __shfl_xor(sq, 1); sq += __shfl_xor(sq, 2);
        const float mean = s * (1.0f / D);
        const float rstd = rsqrtf(sq * (1.0f / D) - mean * mean + 1e-5f);
        #pragma unroll
        for (int q8 = 0; q8 < 8; ++q8) {
            const int c = part * 32 + q8 * 4;
            ushort4 pk;
            pk.x = f2bf((v[q8*4+0] - mean) * rstd * g[c+0] + bt[c+0]);
            pk.y = f2bf((v[q8*4+1] - mean) * rstd * g[c+1] + bt[c+1]);
            pk.z = f2bf((v[q8*4+2] - mean) * rstd * g[c+2] + bt[c+2]);
            pk.w = f2bf((v[q8*4+3] - mean) * rstd * g[c+3] + bt[c+3]);
            *(ushort4*)(&nrm[pr][c]) = pk;
        }
    }
    __syncthreads();

    {
        const int wv = tid >> 6, lane = tid & 63;
        const int lr = lane & 15, lg = lane >> 4;
        f32x4 acc = {0.f, 0.f, 0.f, 0.f};
        #pragma unroll
        for (int ks = 0; ks < 4; ++ks) {
            bf16x8 a = *(const bf16x8*)(&nrm[wv * 16 + lr][ks * 32 + lg * 8]);
            bf16x8 b = *(const bf16x8*)(w1p + (size_t)lr * D + ks * 32 + lg * 8);
            acc = MFMA16(a, b, acc);
        }
        if (lr < NH) {
            #pragma unroll
            for (int r = 0; r < 4; ++r) {
                const int pl = wv * 16 + lg * 4 + r;
                const int pij = ij[pl];
                const int pi = pij >> 16, pj = pij & 0xffff;
                const float val = acc[r] + b1[lr];
                logits[((size_t)pi * L + pj) * NH + lr] = val;
                logits[((size_t)pj * L + pi) * NH + lr] = val;
            }
        }
    }
}

// ---------------------------------------------------------------------------
// Kernel 2: softmax over j for each (i,h); logits f32 -> attnT bf16 [h][i][j]
// ---------------------------------------------------------------------------
__global__ void k_softmax(const float* __restrict__ logits,
                          unsigned short* __restrict__ attnT) {
    const int wave = blockIdx.x * 4 + (threadIdx.x >> 6);
    const int lane = threadIdx.x & 63;
    const int i = wave >> 3, h = wave & 7;

    float v[6];
    float mx = -1e30f;
    #pragma unroll
    for (int t = 0; t < 6; ++t) {
        const int j = lane + t * 64;
        v[t] = logits[((size_t)i * L + j) * NH + h];
        mx = fmaxf(mx, v[t]);
    }
    #pragma unroll
    for (int msk = 32; msk; msk >>= 1) mx = fmaxf(mx, __shfl_xor(mx, msk));

    float s = 0.0f;
    #pragma unroll
    for (int t = 0; t < 6; ++t) { v[t] = __expf(v[t] - mx); s += v[t]; }
    #pragma unroll
    for (int msk = 32; msk; msk >>= 1) s += __shfl_xor(s, msk);
    const float inv = 1.0f / s;

    #pragma unroll
    for (int t = 0; t < 6; ++t) {
        const int j = lane + t * 64;
        attnT[((size_t)h * L + i) * L + j] = f2bf(v[t] * inv);
    }
}

// ---------------------------------------------------------------------------
// Kernel 3: values = LN2(m) @ w2 + b2 -> VtT bf16 [n = r*16+d][j]
// ---------------------------------------------------------------------------
__global__ void k_values(const float* __restrict__ min_,
                         const float* __restrict__ g,
                         const float* __restrict__ bt,
                         const unsigned short* __restrict__ w2p,
                         const float* __restrict__ b2,
                         unsigned short* __restrict__ VtT) {
    __shared__ unsigned short nrm[128][136];
    const int tid = threadIdx.x;
    const int r  = blockIdx.x;
    const int j0 = blockIdx.y * 128;

    #pragma unroll
    for (int half = 0; half < 2; ++half) {
        const int row  = half * 64 + (tid >> 2);
        const int part = tid & 3;
        const float* src = min_ + ((size_t)r * L + j0 + row) * D + part * 32;
        float v[32];
        float s = 0.f, sq = 0.f;
        #pragma unroll
        for (int q = 0; q < 8; ++q) {
            const float4 a = ((const float4*)src)[q];
            v[q*4+0] = a.x; v[q*4+1] = a.y; v[q*4+2] = a.z; v[q*4+3] = a.w;
            s  += a.x + a.y + a.z + a.w;
            sq += a.x*a.x + a.y*a.y + a.z*a.z + a.w*a.w;
        }
        s  += __shfl_xor(s, 1);  s  += __shfl_xor(s, 2);
        sq += __shfl_xor(sq, 1); sq += __shfl_xor(sq, 2);
        const float mean = s * (1.0f / D);
        const float rstd = rsqrtf(sq * (1.0f / D) - mean * mean + 1e-5f);
        #pragma unroll
        for (int q = 0; q < 8; ++q) {
            const int c = part * 32 + q * 4;
            ushort4 pk;
            pk.x = f2bf((v[q*4+0] - mean) * rstd * g[c+0] + bt[c+0]);
            pk.y = f2bf((v[q*4+1] - mean) * rstd * g[c+1] + bt[c+1]);
            pk.z = f2bf((v[q*4+2] - mean) * rstd * g[c+2] + bt[c+2]);
            pk.w = f2bf((v[q*4+3] - mean) * rstd * g[c+3] + bt[c+3]);
            *(ushort4*)(&nrm[row][c]) = pk;
        }
    }
    __syncthreads();

    {
        const int wv = tid >> 6, lane = tid & 63;
        const int lr = lane & 15, lg = lane >> 4;
        f32x4 acc[2];
        acc[0] = (f32x4){0.f, 0.f, 0.f, 0.f};
        acc[1] = (f32x4){0.f, 0.f, 0.f, 0.f};
        #pragma unroll
        for (int ks = 0; ks < 4; ++ks) {
            bf16x8 b = *(const bf16x8*)(w2p + (size_t)lr * D + ks * 32 + lg * 8);
            #pragma unroll
            for (int mt = 0; mt < 2; ++mt) {
                bf16x8 a = *(const bf16x8*)(&nrm[wv * 32 + mt * 16 + lr][ks * 32 + lg * 8]);
                acc[mt] = MFMA16(a, b, acc[mt]);
            }
        }
        const float bb = b2[lr];
        #pragma unroll
        for (int mt = 0; mt < 2; ++mt) {
            ushort4 pk;
            pk.x = f2bf(acc[mt][0] + bb);
            pk.y = f2bf(acc[mt][1] + bb);
            pk.z = f2bf(acc[mt][2] + bb);
            pk.w = f2bf(acc[mt][3] + bb);
            *(ushort4*)(VtT + (size_t)(r * HD + lr) * L + j0 + wv * 32 + mt * 16 + lg * 4) = pk;
        }
    }
}

// ---------------------------------------------------------------------------
// Kernel 4: einsum via MFMA (R13-verified body). Epilogue now writes the
// residual as bf16 outb ONLY (25 MB, L2-resident handoff to k_ffn).
// ---------------------------------------------------------------------------
__global__ void k_attn_out(const unsigned short* __restrict__ attnT,
                           const unsigned short* __restrict__ VtT,
                           const float* __restrict__ min_,
                           unsigned short* __restrict__ outb) {
    const int h  = blockIdx.z;
    const int i0 = blockIdx.x * 128;
    const int n0 = blockIdx.y * 128;
    const int tid = threadIdx.x, wv = tid >> 6, lane = tid & 63;
    const int lr = lane & 15, lg = lane >> 4;
    const int wio = (wv >> 1) * 64, wno = (wv & 1) * 64;
    const unsigned short* Abase = attnT + (size_t)h * L * L;

    f32x4 acc[4][4];
    #pragma unroll
    for (int a = 0; a < 4; ++a)
        #pragma unroll
        for (int b = 0; b < 4; ++b) acc[a][b] = (f32x4){0.f, 0.f, 0.f, 0.f};

    bf16x8 af[4], bf[4], afn[4], bfn[4];
    #pragma unroll
    for (int mt = 0; mt < 4; ++mt)
        af[mt] = *(const bf16x8*)(Abase + (size_t)(i0 + wio + mt * 16 + lr) * L + lg * 8);
    #pragma unroll
    for (int nt = 0; nt < 4; ++nt)
        bf[nt] = *(const bf16x8*)(VtT + (size_t)(n0 + wno + nt * 16 + lr) * L + lg * 8);

    for (int ks = 0; ks < 12; ++ks) {
        if (ks < 11) {
            const int ko = (ks + 1) * 32 + lg * 8;
            #pragma unroll
            for (int mt = 0; mt < 4; ++mt)
                afn[mt] = *(const bf16x8*)(Abase + (size_t)(i0 + wio + mt * 16 + lr) * L + ko);
            #pragma unroll
            for (int nt = 0; nt < 4; ++nt)
                bfn[nt] = *(const bf16x8*)(VtT + (size_t)(n0 + wno + nt * 16 + lr) * L + ko);
        }
        #pragma unroll
        for (int mt = 0; mt < 4; ++mt)
            #pragma unroll
            for (int nt = 0; nt < 4; ++nt)
                acc[mt][nt] = MFMA16(af[mt], bf[nt], acc[mt][nt]);
        #pragma unroll
        for (int q = 0; q < 4; ++q) { af[q] = afn[q]; bf[q] = bfn[q]; }
    }

    #pragma unroll
    for (int mt = 0; mt < 4; ++mt) {
        #pragma unroll
        for (int nt = 0; nt < 4; ++nt) {
            const int nbase = n0 + wno + nt * 16;
            const int rrow  = nbase >> 4;
            #pragma unroll
            for (int r = 0; r < 4; ++r) {
                const int i = i0 + wio + mt * 16 + lg * 4 + r;
                const size_t gidx = ((size_t)rrow * L + i) * D + h * HD + lr;
                outb[gidx] = f2bf(min_[gidx] + acc[mt][nt][r]);
            }
        }
    }
}

// ---------------------------------------------------------------------------
// Kernel 5: FUSED FFN v7 — stages from bf16 outb (L2-resident, no f2bf in
// staging), epilogue writes final f32 out as a pure store (R11 numerics).
// ---------------------------------------------------------------------------
__global__ __launch_bounds__(512, 4) void k_ffn(
                      const unsigned short* __restrict__ outb,
                      const unsigned short* __restrict__ w1gF,
                      const float2* __restrict__ c1c2,
                      const unsigned short* __restrict__ w2tF,
                      const float* __restrict__ ffb2,
                      float* __restrict__ out) {
    __shared__ unsigned short At[64 * 128];     // 16 KB, row-XOR swizzled
    __shared__ unsigned short hid[2][64 * 128]; // 2 x 16 KB, swizzled
    __shared__ float2 stats[64];                // (rstd, mu*rstd)
    const int tid = threadIdx.x;
    const size_t row0 = (size_t)blockIdx.x * 64;

    const int wv = tid >> 6, lane = tid & 63;
    const int lr = lane & 15, lg = lane >> 4;
    const int wm = wv >> 2, wn = wv & 3;          // 2(M:32rows) x 4(N:32cols)

    // ---- preload W1 fragments for kc=0 (overlaps A-staging) ----
    bf16x8 w1f[8], w2f[8];
    #pragma unroll
    for (int ks = 0; ks < 4; ++ks)
        #pragma unroll
        for (int nt = 0; nt < 2; ++nt) {
            const int fi = (0 * 8 + wn * 2 + nt) * 4 + ks;
            w1f[ks * 2 + nt] = *(const bf16x8*)((const char*)w1gF + fi * 1024 + lane * 16);
        }

    // ---- Stage A (bf16 copy) + inline LN3 stats: 8 thr/row x 16 ch ----
    {
        const int rr = tid >> 3, part = tid & 7;
        const unsigned short* src = outb + (row0 + rr) * D + part * 16;
        const uint4 v0 = *(const uint4*)(src);       // 8 bf16
        const uint4 v1 = *(const uint4*)(src + 8);   // 8 bf16
        float s = 0.f, sq = 0.f;
        const unsigned w[8] = {v0.x, v0.y, v0.z, v0.w, v1.x, v1.y, v1.z, v1.w};
        #pragma unroll
        for (int e = 0; e < 8; ++e) {
            const float lo = __builtin_bit_cast(float, w[e] << 16);
            const float hi = __builtin_bit_cast(float, w[e] & 0xffff0000u);
            s  += lo + hi;
            sq += lo * lo + hi * hi;
        }
        s  += __shfl_xor(s, 1);  s  += __shfl_xor(s, 2);  s  += __shfl_xor(s, 4);
        sq += __shfl_xor(sq, 1); sq += __shfl_xor(sq, 2); sq += __shfl_xor(sq, 4);
        if (part == 0) {
            const float mean = s * (1.0f / D);
            const float rstd = rsqrtf(sq * (1.0f / D) - mean * mean + 1e-5f);
            stats[rr] = make_float2(rstd, mean * rstd);
        }
        const int xr = (rr & 7) << 4;
        char* rowp = (char*)(At + rr * 128);
        const int cb = part * 32;                 // byte offset of 16 bf16
        *(uint4*)(rowp + ((cb     ) ^ xr)) = v0;
        *(uint4*)(rowp + ((cb + 16) ^ xr)) = v1;
    }

    // ---- preload W2 fragments for kc=0 ----
    #pragma unroll
    for (int ks = 0; ks < 4; ++ks)
        #pragma unroll
        for (int nt = 0; nt < 2; ++nt) {
            const int fi = (wn * 2 + nt) * 16 + 0 * 4 + ks;
            w2f[ks * 2 + nt] = *(const bf16x8*)((const char*)w2tF + fi * 1024 + lane * 16);
        }

    __syncthreads();

    f32x4 acc2[2][2];
    #pragma unroll
    for (int m = 0; m < 2; ++m)
        #pragma unroll
        for (int n = 0; n < 2; ++n) acc2[m][n] = (f32x4){0.f, 0.f, 0.f, 0.f};

    #pragma unroll
    for (int kc = 0; kc < 4; ++kc) {
        const int p = kc & 1;

        // ---- GEMM1-chunk ----
        {
            f32x4 acc1[2][2];
            #pragma unroll
            for (int m = 0; m < 2; ++m)
                #pragma unroll
                for (int n = 0; n < 2; ++n) acc1[m][n] = (f32x4){0.f, 0.f, 0.f, 0.f};

            #pragma unroll
            for (int ks = 0; ks < 4; ++ks) {
                bf16x8 af[2];
                #pragma unroll
                for (int mt = 0; mt < 2; ++mt) {
                    const int row = wm * 32 + mt * 16 + lr;
                    af[mt] = *(const bf16x8*)((char*)(At + row * 128) +
                              ((ks * 64 + lg * 16) ^ ((row & 7) << 4)));
                }
                #pragma unroll
                for (int mt = 0; mt < 2; ++mt)
                    #pragma unroll
                    for (int nt = 0; nt < 2; ++nt)
                        acc1[mt][nt] = MFMA16(af[mt], w1f[ks * 2 + nt], acc1[mt][nt]);
            }

            #pragma unroll
            for (int nt = 0; nt < 2; ++nt) {
                const int chl = wn * 32 + nt * 16 + lr;        // 0..127
                const float2 cc = c1c2[kc * 128 + chl];
                #pragma unroll
                for (int mt = 0; mt < 2; ++mt) {
                    #pragma unroll
                    for (int r = 0; r < 4; ++r) {
                        const int row = wm * 32 + mt * 16 + lg * 4 + r;
                        const float2 st = stats[row];
                        const float pre = st.x * acc1[mt][nt][r] - st.y * cc.x + cc.y;
                        *(unsigned short*)((char*)(hid[p] + row * 128) +
                            ((chl * 2) ^ ((row & 7) << 4))) = f2bf(fmaxf(pre, 0.f));
                    }
                }
            }
        }
        __syncthreads();

        // refill W1 for kc+1 AFTER the barrier (overlaps GEMM2)
        if (kc < 3) {
            #pragma unroll
            for (int ks = 0; ks < 4; ++ks)
                #pragma unroll
                for (int nt = 0; nt < 2; ++nt) {
                    const int fi = ((kc + 1) * 8 + wn * 2 + nt) * 4 + ks;
                    w1f[ks * 2 + nt] = *(const bf16x8*)((const char*)w1gF + fi * 1024 + lane * 16);
                }
        }

        // ---- GEMM2-chunk ----
        {
            #pragma unroll
            for (int ks = 0; ks < 4; ++ks) {
                bf16x8 hf[2];
                #pragma unroll
                for (int mt = 0; mt < 2; ++mt) {
                    const int row = wm * 32 + mt * 16 + lr;
                    hf[mt] = *(const bf16x8*)((char*)(hid[p] + row * 128) +
                              ((ks * 64 + lg * 16) ^ ((row & 7) << 4)));
                }
                #pragma unroll
                for (int mt = 0; mt < 2; ++mt)
                    #pragma unroll
                    for (int nt = 0; nt < 2; ++nt)
                        acc2[mt][nt] = MFMA16(hf[mt], w2f[ks * 2 + nt], acc2[mt][nt]);
            }
        }

        // refill W2 for kc+1 (overlaps next GEMM1)
        if (kc < 3) {
            #pragma unroll
            for (int ks = 0; ks < 4; ++ks)
                #pragma unroll
                for (int nt = 0; nt < 2; ++nt) {
                    const int fi = (wn * 2 + nt) * 16 + (kc + 1) * 4 + ks;
                    w2f[ks * 2 + nt] = *(const bf16x8*)((const char*)w2tF + fi * 1024 + lane * 16);
                }
        }
    }

    // ---- epilogue: out = bf2f(At) + acc2 + ffb2 (pure store, no RMW) ----
    #pragma unroll
    for (int nt = 0; nt < 2; ++nt) {
        const int ch = wn * 32 + nt * 16 + lr;
        const float bb = ffb2[ch];
        #pragma unroll
        for (int mt = 0; mt < 2; ++mt) {
            #pragma unroll
            for (int r = 0; r < 4; ++r) {
                const int row = wm * 32 + mt * 16 + lg * 4 + r;
                const float resid = bf2f(*(const unsigned short*)((char*)(At + row * 128) +
                                     ((ch * 2) ^ ((row & 7) << 4))));
                out[(row0 + row) * (size_t)D + ch] = resid + acc2[mt][nt][r] + bb;
            }
        }
    }
}

// ---------------------------------------------------------------------------
extern "C" void kernel_launch(void* const* d_in, const int* in_sizes, int n_in,
                              void* d_out, int out_size, void* d_ws, size_t ws_size,
                              hipStream_t stream) {
    const float* x     = (const float*)d_in[0];
    const float* m     = (const float*)d_in[1];
    const float* ln1_g = (const float*)d_in[2];
    const float* ln1_b = (const float*)d_in[3];
    const float* ln2_g = (const float*)d_in[4];
    const float* ln2_b = (const float*)d_in[5];
    const float* ln3_g = (const float*)d_in[6];
    const float* ln3_b = (const float*)d_in[7];
    const float* w1    = (const float*)d_in[8];
    const float* b1    = (const float*)d_in[9];
    const float* w2    = (const float*)d_in[10];
    const float* b2    = (const float*)d_in[11];
    const float* ffw1  = (const float*)d_in[12];
    const float* ffb1  = (const float*)d_in[13];
    const float* ffw2  = (const float*)d_in[14];
    const float* ffb2  = (const float*)d_in[15];

    float* out = (float*)d_out;

    char* wsp = (char*)d_ws;
    float*          logits = (float*)wsp;              wsp += (size_t)L*L*NH*4;   // 4.72 MB
    unsigned short* attnT  = (unsigned short*)wsp;     wsp += (size_t)NH*L*L*2;   // 2.36 MB
    unsigned short* VtT    = (unsigned short*)wsp;     wsp += (size_t)R*HD*L*2;   // 3.15 MB
    unsigned short* w1gF   = (unsigned short*)wsp;     wsp += (size_t)FF*D*2;     // 128 KB
    unsigned short* w2tF   = (unsigned short*)wsp;     wsp += (size_t)D*FF*2;     // 128 KB
    unsigned short* w1p    = (unsigned short*)wsp;     wsp += (size_t)16*D*2;     // 4 KB
    unsigned short* w2p    = (unsigned short*)wsp;     wsp += (size_t)16*D*2;     // 4 KB
    float2*         c1c2   = (float2*)wsp;             wsp += (size_t)FF*8;       // 4 KB
    unsigned short* outb   = (unsigned short*)wsp;     wsp += (size_t)R*L*D*2;    // 25.2 MB

    k_prep<<<(FF * D) / 256, 256, 0, stream>>>(w1, w2, ffw1, ffw2,
                                               ln3_g, ln3_b, ffb1,
                                               w1p, w2p, w1gF, w2tF, c1c2);

    // upper-triangle pair count: 384*385/2 = 73920 -> 1155 blocks of 64
    k_pair_logits<<<1155, 256, 0, stream>>>(x, ln1_g, ln1_b, w1p, b1, logits);
    k_softmax<<<(L * NH) / 4, 256, 0, stream>>>(logits, attnT);

    dim3 g3(R, L / 128);
    k_values<<<g3, 256, 0, stream>>>(m, ln2_g, ln2_b, w2p, b2, VtT);

    dim3 g4(L / 128, (R * HD) / 128, NH);
    k_attn_out<<<g4, 256, 0, stream>>>(attnT, VtT, m, outb);

    k_ffn<<<(R * L) / 64, 512, 0, stream>>>(outb, w1gF, c1c2, w2tF, ffb2, out);
}